// Round 3
// baseline (1029.293 us; speedup 1.0000x reference)
//
#include <hip/hip_runtime.h>
#include <stdint.h>

#define DD 128
#define HN 8
#define NITEMS 81920
#define EINT 163840
#define NT 4096
#define NV 40000
#define NVPAD 40064
#define EAGG 81920
#define NEG_SLOPE 0.2f
#define SCALE 12.0f

typedef unsigned short u16;
typedef __attribute__((ext_vector_type(8))) short bf16x8;
typedef __attribute__((ext_vector_type(4))) float f32x4;
typedef __attribute__((ext_vector_type(4))) unsigned short u16x4;

__device__ __forceinline__ float bf2f(unsigned short u){ return __uint_as_float(((unsigned)u)<<16); }
__device__ __forceinline__ unsigned short f2bf(float f){
  unsigned u = __float_as_uint(f);
  u += 0x7fffu + ((u>>16)&1u);
  return (unsigned short)(u>>16);
}

__global__ __launch_bounds__(256) void k_cast(const float* __restrict__ s, u16* __restrict__ d, int n){
  int i = blockIdx.x*256 + threadIdx.x;
  if (i < n) d[i] = f2bf(s[i]);
}

// U[g*8+h][k], g: 0=l1,1=r1,2=l2,3=r2 ; rows 32..127 pre-zeroed by memset
__global__ __launch_bounds__(128) void k_prep_u(const float* __restrict__ fc1, const float* __restrict__ al1,
    const float* __restrict__ ar1, const float* __restrict__ fc2, const float* __restrict__ al2,
    const float* __restrict__ ar2, u16* __restrict__ U){
  int h = blockIdx.x;     // 0..7
  int k = threadIdx.x;    // 0..127
  float s0=0,s1=0,s2=0,s3=0;
  for (int d=0; d<DD; ++d){
    float w1 = fc1[(size_t)(h*DD+d)*DD + k];
    float w2 = fc2[(size_t)(h*DD+d)*DD + k];
    s0 += w1*al1[h*DD+d];
    s1 += w1*ar1[h*DD+d];
    s2 += w2*al2[h*DD+d];
    s3 += w2*ar2[h*DD+d];
  }
  U[(size_t)(0*8+h)*DD + k] = f2bf(s0);
  U[(size_t)(1*8+h)*DD + k] = f2bf(s1);
  U[(size_t)(2*8+h)*DD + k] = f2bf(s2);
  U[(size_t)(3*8+h)*DD + k] = f2bf(s3);
}

// hv = normalize(emb[iid]) -> f32 + bf16
__global__ __launch_bounds__(256) void k_hv(const float* __restrict__ emb, const int* __restrict__ iid,
                                            float* __restrict__ hv, u16* __restrict__ hvb, int n){
  int w = (blockIdx.x*256 + threadIdx.x) >> 6;
  int lane = threadIdx.x & 63;
  if (w >= n) return;
  const float* src = emb + (size_t)iid[w]*DD;
  float2 v = *(const float2*)(src + lane*2);
  float ss = v.x*v.x + v.y*v.y;
  #pragma unroll
  for (int m=1;m<64;m<<=1) ss += __shfl_xor(ss, m);
  float inv = 1.f / fmaxf(sqrtf(ss), 1e-12f);
  float a = v.x*inv, b = v.y*inv;
  float2 o; o.x=a; o.y=b;
  *(float2*)(hv + (size_t)w*DD + lane*2) = o;
  hvb[(size_t)w*DD + lane*2]     = f2bf(a);
  hvb[(size_t)w*DD + lane*2 + 1] = f2bf(b);
}

// normalized emb (all 40000 rows) as bf16, padded to NVPAD rows (pad = 0)
__global__ __launch_bounds__(256) void k_nemb(const float* __restrict__ emb, u16* __restrict__ nb){
  int w = (blockIdx.x*256 + threadIdx.x) >> 6;
  int lane = threadIdx.x & 63;
  if (w >= NVPAD) return;
  if (w >= NV){ nb[(size_t)w*DD+lane*2]=0; nb[(size_t)w*DD+lane*2+1]=0; return; }
  const float* src = emb + (size_t)w*DD;
  float2 v = *(const float2*)(src + lane*2);
  float ss = v.x*v.x + v.y*v.y;
  #pragma unroll
  for (int m=1;m<64;m<<=1) ss += __shfl_xor(ss, m);
  float inv = 1.f / fmaxf(sqrtf(ss), 1e-12f);
  nb[(size_t)w*DD+lane*2]   = f2bf(v.x*inv);
  nb[(size_t)w*DD+lane*2+1] = f2bf(v.y*inv);
}

// generic NT GEMM, 128x128 tile, K-loop of 32 (used for ecat and ep)
template<int OUT_BF16>
__global__ __launch_bounds__(256) void gemm_nt(const u16* __restrict__ A, const u16* __restrict__ B,
                                               void* __restrict__ C, int M, int N, int K,
                                               float alpha, int ldc, int nvalid){
  __shared__ u16 As[128*32];
  __shared__ u16 Bs[128*32];
  int m0 = blockIdx.x*128, n0 = blockIdx.y*128;
  int t = threadIdx.x, lane = t&63, wid = t>>6;
  int wm = wid>>1, wn = wid&1;
  f32x4 zero = {0.f,0.f,0.f,0.f};
  f32x4 acc[4][4];
  #pragma unroll
  for (int i=0;i<4;i++)
    #pragma unroll
    for (int j=0;j<4;j++) acc[i][j] = zero;
  int lr = lane & 15, lk = (lane>>4)*8;
  for (int k0=0; k0<K; k0+=32){
    #pragma unroll
    for (int cc=0; cc<2; ++cc){
      int c = t + cc*256;
      int row = c>>2, col = (c&3)*8;
      *(bf16x8*)(void*)&As[c*8] = *(const bf16x8*)(const void*)&A[(size_t)(m0+row)*K + k0 + col];
      *(bf16x8*)(void*)&Bs[c*8] = *(const bf16x8*)(const void*)&B[(size_t)(n0+row)*K + k0 + col];
    }
    __syncthreads();
    bf16x8 af[4], bfr[4];
    #pragma unroll
    for (int m=0;m<4;m++) af[m]  = *(const bf16x8*)(const void*)&As[(wm*64+m*16+lr)*32 + lk];
    #pragma unroll
    for (int n=0;n<4;n++) bfr[n] = *(const bf16x8*)(const void*)&Bs[(wn*64+n*16+lr)*32 + lk];
    #pragma unroll
    for (int m=0;m<4;m++)
      #pragma unroll
      for (int n=0;n<4;n++)
        acc[m][n] = __builtin_amdgcn_mfma_f32_16x16x32_bf16(af[m], bfr[n], acc[m][n], 0,0,0);
    __syncthreads();
  }
  #pragma unroll
  for (int m=0;m<4;m++)
    #pragma unroll
    for (int n=0;n<4;n++)
      #pragma unroll
      for (int r=0;r<4;r++){
        int row = m0 + wm*64 + m*16 + (lane>>4)*4 + r;
        int col = n0 + wn*64 + n*16 + (lane&15);
        if (col < nvalid){
          float v = acc[m][n][r]*alpha;
          if (OUT_BF16) ((u16*)C)[(size_t)row*ldc + col] = f2bf(v);
          else          ((float*)C)[(size_t)row*ldc + col] = v;
        }
      }
}

// ---- combined CSR for both graphs (keys: dst_i | NITEMS+src_i) ----
__global__ __launch_bounds__(256) void k_deg2(const int* __restrict__ di, const int* __restrict__ si,
                                              int* __restrict__ cnt){
  int i = blockIdx.x*256+threadIdx.x;
  if (i<EINT){ atomicAdd(&cnt[di[i]],1); atomicAdd(&cnt[NITEMS+si[i]],1); }
}

__global__ __launch_bounds__(256) void k_scan_a(int* cnt, int* off, int* bsum, int n){
  __shared__ int buf[256];
  int b = blockIdx.x, t = threadIdx.x, i = b*256+t;
  int v = (i<n)? cnt[i] : 0;
  buf[t] = v; __syncthreads();
  #pragma unroll
  for (int ofs=1; ofs<256; ofs<<=1){
    int x = (t>=ofs)? buf[t-ofs] : 0;
    __syncthreads();
    buf[t] += x;
    __syncthreads();
  }
  if (i<n){ off[i] = buf[t]-v; cnt[i] = 0; }
  if (t==255) bsum[b] = buf[255];
}

__global__ __launch_bounds__(1024) void k_scan_b(int* bsum, int* off, int nb, int n){
  __shared__ int buf[1024];
  int t = threadIdx.x;
  int v = (t<nb)? bsum[t] : 0;
  buf[t]=v; __syncthreads();
  #pragma unroll
  for (int ofs=1; ofs<1024; ofs<<=1){
    int x=(t>=ofs)?buf[t-ofs]:0; __syncthreads(); buf[t]+=x; __syncthreads();
  }
  if (t<nb) bsum[t] = buf[t]-v;
  if (t==1023) off[n] = buf[1023];
}

__global__ __launch_bounds__(256) void k_scan_c(int* __restrict__ off, const int* __restrict__ bsum, int n){
  int i = blockIdx.x*256+threadIdx.x;
  if (i<n) off[i] += bsum[blockIdx.x];
}

__global__ __launch_bounds__(256) void k_scatter2(const int* __restrict__ di, const int* __restrict__ si,
    const int* __restrict__ off, int* __restrict__ cnt, int* __restrict__ eid){
  int i = blockIdx.x*256+threadIdx.x;
  if (i<EINT){
    int a = di[i];         eid[off[a]+atomicAdd(&cnt[a],1)] = i;
    int b = NITEMS+si[i];  eid[off[b]+atomicAdd(&cnt[b],1)] = i;
  }
}

// One wave per destination node: 8-head edge softmax + weighted aggregation of hv (D=128 space).
// agg[w][h*128+d] = sum_e a_e^h * hv[other_e][d]   (bf16)
__global__ __launch_bounds__(256) void k_agg(const int* __restrict__ off, const int* __restrict__ eid,
    const int* __restrict__ other, const float* __restrict__ el, const float* __restrict__ er,
    const u16* __restrict__ hvb, u16* __restrict__ agg, int obase){
  int w = (blockIdx.x*256 + threadIdx.x) >> 6;
  int lane = threadIdx.x & 63;
  if (w >= NITEMS) return;
  int lo = off[obase+w], hi = off[obase+w+1];
  float ern[8], mh[8];
  #pragma unroll
  for (int h=0;h<8;h++){ ern[h] = er[(size_t)w*32+h]; mh[h] = -1e30f; }
  for (int idx=lo; idx<hi; ++idx){
    int s = other[eid[idx]];
    #pragma unroll
    for (int h=0;h<8;h++){
      float lv = el[(size_t)s*32+h] + ern[h];
      lv = (lv>=0.f)? lv : NEG_SLOPE*lv;
      mh[h] = fmaxf(mh[h], lv);
    }
  }
  float den[8], a0[8], a1[8];
  #pragma unroll
  for (int h=0;h<8;h++){ den[h]=0.f; a0[h]=0.f; a1[h]=0.f; }
  for (int idx=lo; idx<hi; ++idx){
    int s = other[eid[idx]];
    unsigned v = *(const unsigned*)(const void*)(hvb + (size_t)s*DD + lane*2);
    float f0 = bf2f((u16)(v&0xffffu)), f1 = bf2f((u16)(v>>16));
    #pragma unroll
    for (int h=0;h<8;h++){
      float lv = el[(size_t)s*32+h] + ern[h];
      lv = (lv>=0.f)? lv : NEG_SLOPE*lv;
      float wt = expf(lv - mh[h]);
      den[h] += wt; a0[h] += wt*f0; a1[h] += wt*f1;
    }
  }
  #pragma unroll
  for (int h=0;h<8;h++){
    float inv = (den[h]>0.f)? 1.f/den[h] : 0.f;
    unsigned o = (unsigned)f2bf(a0[h]*inv) | ((unsigned)f2bf(a1[h]*inv)<<16);
    *(unsigned*)(void*)(agg + (size_t)w*1024 + h*DD + lane*2) = o;
  }
}

// Batched per-head GEMM: for each head h, rst_h = agg_h[128 x 128] @ fc_h^T, then
// running max over heads of (rst_h + b_h); epilogue adds hv residual.
// MODE 0: h1 = max + hv.  MODE 1: h = normalize(h1 + max + hv) -> h1 (f32, in place) + hb (bf16).
template<int MODE>
__global__ __launch_bounds__(256) void k_headgemm(const u16* __restrict__ agg, const u16* __restrict__ wfc,
    const float* __restrict__ bias, const float* __restrict__ hv, float* __restrict__ h1,
    u16* __restrict__ hb){
  __shared__ u16 As[128*128];
  __shared__ u16 Bs[128*128];
  int n0 = blockIdx.x*128;
  int t = threadIdx.x, lane = t&63, wid = t>>6;
  int lr = lane&15, lq = lane>>4;
  float rm[2][8][4];
  #pragma unroll
  for (int m=0;m<2;m++)
    #pragma unroll
    for (int n=0;n<8;n++)
      #pragma unroll
      for (int r=0;r<4;r++) rm[m][n][r] = -1e30f;

  for (int h=0; h<HN; ++h){
    __syncthreads();
    #pragma unroll
    for (int i=0;i<8;++i){
      int c = t + i*256; int row = c>>4, cc = c&15;
      int dst = row*128 + ((cc ^ (row&7))*8);   // XOR-swizzled 16B chunks
      *(bf16x8*)(void*)&As[dst] = *(const bf16x8*)(const void*)&agg[(size_t)(n0+row)*1024 + h*DD + cc*8];
      *(bf16x8*)(void*)&Bs[dst] = *(const bf16x8*)(const void*)&wfc[(size_t)(h*DD+row)*DD + cc*8];
    }
    __syncthreads();
    f32x4 zero = {0.f,0.f,0.f,0.f};
    f32x4 acc[2][8];
    #pragma unroll
    for (int m=0;m<2;m++)
      #pragma unroll
      for (int n=0;n<8;n++) acc[m][n] = zero;
    #pragma unroll
    for (int ks=0; ks<4; ++ks){
      bf16x8 af[2], bfr[8];
      int ccA = ks*4 + lq;
      #pragma unroll
      for (int m=0;m<2;m++){
        int row = wid*32 + m*16 + lr;
        af[m] = *(const bf16x8*)(const void*)&As[row*128 + ((ccA ^ (row&7))*8)];
      }
      #pragma unroll
      for (int n=0;n<8;n++){
        int row = n*16 + lr;
        bfr[n] = *(const bf16x8*)(const void*)&Bs[row*128 + ((ccA ^ (row&7))*8)];
      }
      #pragma unroll
      for (int m=0;m<2;m++)
        #pragma unroll
        for (int n=0;n<8;n++)
          acc[m][n] = __builtin_amdgcn_mfma_f32_16x16x32_bf16(af[m], bfr[n], acc[m][n], 0,0,0);
    }
    #pragma unroll
    for (int n=0;n<8;n++){
      float bn = bias[h*DD + n*16 + lr];
      #pragma unroll
      for (int m=0;m<2;m++)
        #pragma unroll
        for (int r=0;r<4;r++)
          rm[m][n][r] = fmaxf(rm[m][n][r], acc[m][n][r] + bn);
    }
  }
  // epilogue
  if (MODE==0){
    #pragma unroll
    for (int m=0;m<2;m++)
      #pragma unroll
      for (int n=0;n<8;n++)
        #pragma unroll
        for (int r=0;r<4;r++){
          int grow = n0 + wid*32 + m*16 + lq*4 + r;
          int col = n*16 + lr;
          h1[(size_t)grow*DD + col] = rm[m][n][r] + hv[(size_t)grow*DD + col];
        }
  } else {
    #pragma unroll
    for (int m=0;m<2;m++)
      #pragma unroll
      for (int n=0;n<8;n++)
        #pragma unroll
        for (int r=0;r<4;r++){
          int grow = n0 + wid*32 + m*16 + lq*4 + r;
          int col = n*16 + lr;
          rm[m][n][r] += hv[(size_t)grow*DD + col] + h1[(size_t)grow*DD + col];
        }
    #pragma unroll
    for (int m=0;m<2;m++)
      #pragma unroll
      for (int r=0;r<4;r++){
        float ss = 0.f;
        #pragma unroll
        for (int n=0;n<8;n++) ss += rm[m][n][r]*rm[m][n][r];
        ss += __shfl_xor(ss,1); ss += __shfl_xor(ss,2);
        ss += __shfl_xor(ss,4); ss += __shfl_xor(ss,8);
        float inv = 1.f/fmaxf(sqrtf(ss),1e-12f);
        int grow = n0 + wid*32 + m*16 + lq*4 + r;
        #pragma unroll
        for (int n=0;n<8;n++){
          float o = rm[m][n][r]*inv;
          int col = n*16 + lr;
          h1[(size_t)grow*DD + col] = o;
          hb[(size_t)grow*DD + col] = f2bf(o);
        }
      }
  }
}

// cat[i] = [ hb[agg_src[i]] | f2bf(pos_emb[pid[i]]) ]  (bf16, [EAGG,256]); 4 elems/thread
__global__ __launch_bounds__(256) void k_cat(const u16* __restrict__ hb, const float* __restrict__ pemb,
    const int* __restrict__ pid, const int* __restrict__ asrc, u16* __restrict__ cat){
  int idx = blockIdx.x*256 + threadIdx.x;
  if (idx >= EAGG*32) return;
  int i = idx >> 5;
  int c = (idx & 31) * 4;
  int s = asrc[i], p = pid[i];
  *(u16x4*)(void*)(cat + (size_t)i*256 + c) = *(const u16x4*)(const void*)(hb + (size_t)s*DD + c);
  float4 b = *(const float4*)(pemb + (size_t)p*DD + c);
  u16x4 ob = {f2bf(b.x),f2bf(b.y),f2bf(b.z),f2bf(b.w)};
  *(u16x4*)(void*)(cat + (size_t)i*256 + DD + c) = ob;
}

// w[i] = sum_j tanh(ep[i,j]) * target_emb[tid[agg_dst[i]], j]   (ep bf16)
__global__ __launch_bounds__(256) void k_w(const u16* __restrict__ ep, const int* __restrict__ adst,
    const int* __restrict__ tid_, const float* __restrict__ temb, float* __restrict__ w){
  int i = (blockIdx.x*256 + threadIdx.x) >> 6;
  int lane = threadIdx.x & 63;
  if (i >= EAGG) return;
  int t = adst[i];
  int tt = tid_[t];
  unsigned v = *(const unsigned*)(const void*)(ep + (size_t)i*DD + lane*2);
  float e0 = tanhf(bf2f((u16)(v&0xffffu)));
  float e1 = tanhf(bf2f((u16)(v>>16)));
  float2 te = *(const float2*)(temb + (size_t)tt*DD + lane*2);
  float s = e0*te.x + e1*te.y;
  #pragma unroll
  for (int m=1;m<64;m<<=1) s += __shfl_xor(s,m);
  if (lane==0) w[i] = s;
}

__device__ __forceinline__ int lbound(const int* a, int n, int key){
  int lo=0, hi=n;
  while (lo<hi){ int mid=(lo+hi)>>1; if (a[mid]<key) lo=mid+1; else hi=mid; }
  return lo;
}

// per-target: sr_g (segment sum over sorted agg_dst), concat with h[last], matmul fc_sr, normalize -> nsr bf16
__global__ __launch_bounds__(256) void k_sr(const float* __restrict__ h, const float* __restrict__ w,
    const int* __restrict__ asrc, const int* __restrict__ adst, const int* __restrict__ lastn,
    const float* __restrict__ fcsr, u16* __restrict__ nsr){
  __shared__ float cat[256];
  __shared__ float red[128];
  __shared__ int lohi[2];
  int t = blockIdx.x, tid = threadIdx.x;
  if (tid == 0){ lohi[0] = lbound(adst, EAGG, t); lohi[1] = lbound(adst, EAGG, t+1); }
  __syncthreads();
  int lo = lohi[0], hi = lohi[1];
  if (tid < DD){
    float a = 0.f;
    for (int i=lo;i<hi;++i) a += h[(size_t)asrc[i]*DD + tid] * w[i];
    cat[tid] = a;
  } else {
    int d = tid - DD;
    cat[DD + d] = h[(size_t)lastn[t]*DD + d];
  }
  __syncthreads();
  float s = 0.f;
  if (tid < DD){
    const float* row = fcsr + (size_t)tid*256;
    #pragma unroll 8
    for (int k=0;k<256;++k) s += cat[k]*row[k];
    red[tid] = s*s;
  }
  __syncthreads();
  for (int st=64; st>0; st>>=1){
    if (tid < st) red[tid] += red[tid+st];
    __syncthreads();
  }
  if (tid < DD){
    float inv = 1.f/fmaxf(sqrtf(red[0]),1e-12f);
    nsr[(size_t)t*DD + tid] = f2bf(s*inv);
  }
}

// scores GEMM: full-K(128) single-stage LDS, 128x128 tile, XOR-swizzled
__global__ __launch_bounds__(256) void gemm_sc(const u16* __restrict__ A, const u16* __restrict__ B,
                                               float* __restrict__ C){
  __shared__ u16 As[128*128];
  __shared__ u16 Bs[128*128];
  int m0 = blockIdx.x*128, n0 = blockIdx.y*128;
  int t = threadIdx.x, lane = t&63, wid = t>>6;
  int wm = wid>>1, wn = wid&1, lr = lane&15, lq = lane>>4;
  #pragma unroll
  for (int i=0;i<8;++i){
    int c = t + i*256; int row=c>>4, cc=c&15;
    int dst = row*128 + ((cc ^ (row&7))*8);
    *(bf16x8*)(void*)&As[dst] = *(const bf16x8*)(const void*)&A[(size_t)(m0+row)*DD + cc*8];
    *(bf16x8*)(void*)&Bs[dst] = *(const bf16x8*)(const void*)&B[(size_t)(n0+row)*DD + cc*8];
  }
  __syncthreads();
  f32x4 zero = {0.f,0.f,0.f,0.f};
  f32x4 acc[4][4];
  #pragma unroll
  for (int m=0;m<4;m++)
    #pragma unroll
    for (int n=0;n<4;n++) acc[m][n] = zero;
  #pragma unroll
  for (int ks=0;ks<4;++ks){
    bf16x8 af[4], bfr[4];
    int ccA = ks*4 + lq;
    #pragma unroll
    for (int m=0;m<4;m++){
      int row = wm*64 + m*16 + lr;
      af[m] = *(const bf16x8*)(const void*)&As[row*128 + ((ccA ^ (row&7))*8)];
    }
    #pragma unroll
    for (int n=0;n<4;n++){
      int row = wn*64 + n*16 + lr;
      bfr[n] = *(const bf16x8*)(const void*)&Bs[row*128 + ((ccA ^ (row&7))*8)];
    }
    #pragma unroll
    for (int m=0;m<4;m++)
      #pragma unroll
      for (int n=0;n<4;n++)
        acc[m][n] = __builtin_amdgcn_mfma_f32_16x16x32_bf16(af[m], bfr[n], acc[m][n], 0,0,0);
  }
  #pragma unroll
  for (int m=0;m<4;m++)
    #pragma unroll
    for (int n=0;n<4;n++)
      #pragma unroll
      for (int r=0;r<4;r++){
        int row = m0 + wm*64 + m*16 + lq*4 + r;
        int col = n0 + wn*64 + n*16 + lr;
        if (col < NV) C[(size_t)row*NV + col] = acc[m][n][r]*SCALE;
      }
}

extern "C" void kernel_launch(void* const* d_in, const int* in_sizes, int n_in,
                              void* d_out, int out_size, void* d_ws, size_t ws_size,
                              hipStream_t stream){
  (void)in_sizes; (void)n_in; (void)out_size; (void)ws_size;
  const int*   iid   = (const int*)d_in[0];
  const int*   tid_  = (const int*)d_in[1];
  const int*   pid   = (const int*)d_in[2];
  const int*   src_i = (const int*)d_in[3];
  const int*   dst_i = (const int*)d_in[4];
  const int*   asrc  = (const int*)d_in[5];
  const int*   adst  = (const int*)d_in[6];
  const int*   lastn = (const int*)d_in[7];
  const float* emb   = (const float*)d_in[8];
  const float* pemb  = (const float*)d_in[9];
  const float* temb  = (const float*)d_in[10];
  const float* fc1   = (const float*)d_in[11];
  const float* al1   = (const float*)d_in[12];
  const float* ar1   = (const float*)d_in[13];
  const float* b1    = (const float*)d_in[14];
  const float* fc2   = (const float*)d_in[15];
  const float* al2   = (const float*)d_in[16];
  const float* ar2   = (const float*)d_in[17];
  const float* b2    = (const float*)d_in[18];
  const float* qw    = (const float*)d_in[19];
  const float* fcsr  = (const float*)d_in[20];

  char* ws = (char*)d_ws;
  size_t o = 0;
  auto alc = [&](size_t b)->char*{ char* r = ws + o; o += (b + 511) & ~(size_t)511; return r; };
  float* hv   = (float*)alc((size_t)NITEMS*DD*4);      // 42 MB
  u16*   hvb  = (u16*)  alc((size_t)NITEMS*DD*2);      // 21 MB (later reused as hb)
  float* h1   = (float*)alc((size_t)NITEMS*DD*4);      // 42 MB (h1, then h in-place)
  float* ecat = (float*)alc((size_t)NITEMS*32*4);      // 10.5 MB (el1|er1|el2|er2)
  int*   off  = (int*)  alc((size_t)(2*NITEMS+1)*4);
  int*   cnt  = (int*)  alc((size_t)(2*NITEMS)*4);
  int*   bsum = (int*)  alc((size_t)1024*4);
  int*   eid  = (int*)  alc((size_t)(2*EINT)*4);
  u16*   wfc1 = (u16*)  alc((size_t)1024*DD*2);
  u16*   wfc2 = (u16*)  alc((size_t)1024*DD*2);
  u16*   qwb  = (u16*)  alc((size_t)DD*256*2);
  u16*   Umat = (u16*)  alc((size_t)128*DD*2);
  float* wv   = (float*)alc((size_t)EAGG*4);
  u16*   nsr  = (u16*)  alc((size_t)NT*DD*2);
  u16*   nemb = (u16*)  alc((size_t)NVPAD*DD*2);       // 10.3 MB
  u16*   agg  = (u16*)  alc((size_t)NITEMS*1024*2);    // 168 MB (later aliased by cat/ep)
  u16*   hb   = hvb;
  u16*   catb = agg;
  u16*   epb  = agg + (size_t)EAGG*256;

  const int N2 = 2*NITEMS;
  const int NB2 = N2/256;    // 640

  // ---- precompute ----
  hipMemsetAsync(Umat, 0, (size_t)128*DD*2, stream);
  k_prep_u<<<8, 128, 0, stream>>>(fc1, al1, ar1, fc2, al2, ar2, Umat);
  k_hv  <<<NITEMS/4, 256, 0, stream>>>(emb, iid, hv, hvb, NITEMS);
  k_nemb<<<NVPAD/4,  256, 0, stream>>>(emb, nemb);
  k_cast<<<512, 256, 0, stream>>>(fc1, wfc1, 1024*DD);
  k_cast<<<512, 256, 0, stream>>>(fc2, wfc2, 1024*DD);
  k_cast<<<128, 256, 0, stream>>>(qw, qwb, DD*256);
  gemm_nt<0><<<dim3(NITEMS/128, 1), 256, 0, stream>>>(hvb, Umat, ecat, NITEMS, 128, DD, 1.f, 32, 32);

  // ---- combined CSR (graph1 keyed by dst_i at [0,N), graph2 keyed by src_i at [N,2N)) ----
  hipMemsetAsync(cnt, 0, (size_t)N2*4, stream);
  k_deg2<<<(EINT+255)/256, 256, 0, stream>>>(dst_i, src_i, cnt);
  k_scan_a<<<NB2, 256, 0, stream>>>(cnt, off, bsum, N2);
  k_scan_b<<<1, 1024, 0, stream>>>(bsum, off, NB2, N2);
  k_scan_c<<<NB2, 256, 0, stream>>>(off, bsum, N2);
  k_scatter2<<<(EINT+255)/256, 256, 0, stream>>>(dst_i, src_i, off, cnt, eid);

  // ---- GAT1 ----
  k_agg<<<NITEMS/4, 256, 0, stream>>>(off, eid, src_i, ecat+0, ecat+8, hvb, agg, 0);
  k_headgemm<0><<<NITEMS/128, 256, 0, stream>>>(agg, wfc1, b1, hv, h1, nullptr);

  // ---- GAT2 (reversed) ----
  k_agg<<<NITEMS/4, 256, 0, stream>>>(off, eid, dst_i, ecat+16, ecat+24, hvb, agg, NITEMS);
  k_headgemm<1><<<NITEMS/128, 256, 0, stream>>>(agg, wfc2, b2, hv, h1, hb);

  // ---- PosAggregator ----
  k_cat<<<(EAGG*32)/256, 256, 0, stream>>>(hb, pemb, pid, asrc, catb);
  gemm_nt<1><<<dim3(EAGG/128, 1), 256, 0, stream>>>(catb, qwb, epb, EAGG, 128, 256, 1.f, 128, 128);
  k_w<<<EAGG/4, 256, 0, stream>>>(epb, adst, tid_, temb, wv);
  k_sr<<<NT, 256, 0, stream>>>(h1, wv, asrc, adst, lastn, fcsr, nsr);

  // ---- scores = SCALE * nsr @ nemb^T ----
  gemm_sc<<<dim3(NT/128, NVPAD/128), 256, 0, stream>>>(nsr, nemb, (float*)d_out);
}

// Round 4
// 832.466 us; speedup vs baseline: 1.2364x; 1.2364x over previous
//
#include <hip/hip_runtime.h>
#include <stdint.h>

#define DD 128
#define HN 8
#define NITEMS 81920
#define EINT 163840
#define NT 4096
#define NV 40000
#define NVPAD 40064
#define EAGG 81920
#define NEG_SLOPE 0.2f
#define SCALE 12.0f

typedef unsigned short u16;
typedef __attribute__((ext_vector_type(8))) short bf16x8;
typedef __attribute__((ext_vector_type(4))) float f32x4;
typedef __attribute__((ext_vector_type(4))) unsigned short u16x4;

__device__ __forceinline__ float bf2f(unsigned short u){ return __uint_as_float(((unsigned)u)<<16); }
__device__ __forceinline__ unsigned short f2bf(float f){
  unsigned u = __float_as_uint(f);
  u += 0x7fffu + ((u>>16)&1u);
  return (unsigned short)(u>>16);
}

__global__ __launch_bounds__(256) void k_cast(const float* __restrict__ s, u16* __restrict__ d, int n){
  int i = blockIdx.x*256 + threadIdx.x;
  if (i < n) d[i] = f2bf(s[i]);
}

// U[g*8+h][k], g: 0=l1,1=r1,2=l2,3=r2 ; rows 32..127 pre-zeroed by memset
__global__ __launch_bounds__(128) void k_prep_u(const float* __restrict__ fc1, const float* __restrict__ al1,
    const float* __restrict__ ar1, const float* __restrict__ fc2, const float* __restrict__ al2,
    const float* __restrict__ ar2, u16* __restrict__ U){
  int h = blockIdx.x;     // 0..7
  int k = threadIdx.x;    // 0..127
  float s0=0,s1=0,s2=0,s3=0;
  for (int d=0; d<DD; ++d){
    float w1 = fc1[(size_t)(h*DD+d)*DD + k];
    float w2 = fc2[(size_t)(h*DD+d)*DD + k];
    s0 += w1*al1[h*DD+d];
    s1 += w1*ar1[h*DD+d];
    s2 += w2*al2[h*DD+d];
    s3 += w2*ar2[h*DD+d];
  }
  U[(size_t)(0*8+h)*DD + k] = f2bf(s0);
  U[(size_t)(1*8+h)*DD + k] = f2bf(s1);
  U[(size_t)(2*8+h)*DD + k] = f2bf(s2);
  U[(size_t)(3*8+h)*DD + k] = f2bf(s3);
}

// hv = normalize(emb[iid]) -> f32 + bf16
__global__ __launch_bounds__(256) void k_hv(const float* __restrict__ emb, const int* __restrict__ iid,
                                            float* __restrict__ hv, u16* __restrict__ hvb, int n){
  int w = (blockIdx.x*256 + threadIdx.x) >> 6;
  int lane = threadIdx.x & 63;
  if (w >= n) return;
  const float* src = emb + (size_t)iid[w]*DD;
  float2 v = *(const float2*)(src + lane*2);
  float ss = v.x*v.x + v.y*v.y;
  #pragma unroll
  for (int m=1;m<64;m<<=1) ss += __shfl_xor(ss, m);
  float inv = 1.f / fmaxf(sqrtf(ss), 1e-12f);
  float a = v.x*inv, b = v.y*inv;
  float2 o; o.x=a; o.y=b;
  *(float2*)(hv + (size_t)w*DD + lane*2) = o;
  hvb[(size_t)w*DD + lane*2]     = f2bf(a);
  hvb[(size_t)w*DD + lane*2 + 1] = f2bf(b);
}

// normalized emb (all 40000 rows) as bf16, padded to NVPAD rows (pad = 0)
__global__ __launch_bounds__(256) void k_nemb(const float* __restrict__ emb, u16* __restrict__ nb){
  int w = (blockIdx.x*256 + threadIdx.x) >> 6;
  int lane = threadIdx.x & 63;
  if (w >= NVPAD) return;
  if (w >= NV){ nb[(size_t)w*DD+lane*2]=0; nb[(size_t)w*DD+lane*2+1]=0; return; }
  const float* src = emb + (size_t)w*DD;
  float2 v = *(const float2*)(src + lane*2);
  float ss = v.x*v.x + v.y*v.y;
  #pragma unroll
  for (int m=1;m<64;m<<=1) ss += __shfl_xor(ss, m);
  float inv = 1.f / fmaxf(sqrtf(ss), 1e-12f);
  nb[(size_t)w*DD+lane*2]   = f2bf(v.x*inv);
  nb[(size_t)w*DD+lane*2+1] = f2bf(v.y*inv);
}

// generic NT GEMM, 128x128 tile, K-loop of 32 (ecat, ep, scores). 16 KB LDS -> high occupancy.
template<int OUT_BF16>
__global__ __launch_bounds__(256) void gemm_nt(const u16* __restrict__ A, const u16* __restrict__ B,
                                               void* __restrict__ C, int M, int N, int K,
                                               float alpha, int ldc, int nvalid){
  __shared__ u16 As[128*32];
  __shared__ u16 Bs[128*32];
  int m0 = blockIdx.x*128, n0 = blockIdx.y*128;
  int t = threadIdx.x, lane = t&63, wid = t>>6;
  int wm = wid>>1, wn = wid&1;
  f32x4 zero = {0.f,0.f,0.f,0.f};
  f32x4 acc[4][4];
  #pragma unroll
  for (int i=0;i<4;i++)
    #pragma unroll
    for (int j=0;j<4;j++) acc[i][j] = zero;
  int lr = lane & 15, lk = (lane>>4)*8;
  for (int k0=0; k0<K; k0+=32){
    #pragma unroll
    for (int cc=0; cc<2; ++cc){
      int c = t + cc*256;
      int row = c>>2, col = (c&3)*8;
      *(bf16x8*)(void*)&As[c*8] = *(const bf16x8*)(const void*)&A[(size_t)(m0+row)*K + k0 + col];
      *(bf16x8*)(void*)&Bs[c*8] = *(const bf16x8*)(const void*)&B[(size_t)(n0+row)*K + k0 + col];
    }
    __syncthreads();
    bf16x8 af[4], bfr[4];
    #pragma unroll
    for (int m=0;m<4;m++) af[m]  = *(const bf16x8*)(const void*)&As[(wm*64+m*16+lr)*32 + lk];
    #pragma unroll
    for (int n=0;n<4;n++) bfr[n] = *(const bf16x8*)(const void*)&Bs[(wn*64+n*16+lr)*32 + lk];
    #pragma unroll
    for (int m=0;m<4;m++)
      #pragma unroll
      for (int n=0;n<4;n++)
        acc[m][n] = __builtin_amdgcn_mfma_f32_16x16x32_bf16(af[m], bfr[n], acc[m][n], 0,0,0);
    __syncthreads();
  }
  #pragma unroll
  for (int m=0;m<4;m++)
    #pragma unroll
    for (int n=0;n<4;n++)
      #pragma unroll
      for (int r=0;r<4;r++){
        int row = m0 + wm*64 + m*16 + (lane>>4)*4 + r;
        int col = n0 + wn*64 + n*16 + (lane&15);
        if (col < nvalid){
          float v = acc[m][n][r]*alpha;
          if (OUT_BF16) ((u16*)C)[(size_t)row*ldc + col] = f2bf(v);
          else          ((float*)C)[(size_t)row*ldc + col] = v;
        }
      }
}

// ---- combined CSR for both graphs (keys: dst_i | NITEMS+src_i); sid stores the OTHER endpoint ----
__global__ __launch_bounds__(256) void k_deg2(const int* __restrict__ di, const int* __restrict__ si,
                                              int* __restrict__ cnt){
  int i = blockIdx.x*256+threadIdx.x;
  if (i<EINT){ atomicAdd(&cnt[di[i]],1); atomicAdd(&cnt[NITEMS+si[i]],1); }
}

__global__ __launch_bounds__(256) void k_scan_a(int* cnt, int* off, int* bsum, int n){
  __shared__ int buf[256];
  int b = blockIdx.x, t = threadIdx.x, i = b*256+t;
  int v = (i<n)? cnt[i] : 0;
  buf[t] = v; __syncthreads();
  #pragma unroll
  for (int ofs=1; ofs<256; ofs<<=1){
    int x = (t>=ofs)? buf[t-ofs] : 0;
    __syncthreads();
    buf[t] += x;
    __syncthreads();
  }
  if (i<n){ off[i] = buf[t]-v; cnt[i] = 0; }
  if (t==255) bsum[b] = buf[255];
}

__global__ __launch_bounds__(1024) void k_scan_b(int* bsum, int* off, int nb, int n){
  __shared__ int buf[1024];
  int t = threadIdx.x;
  int v = (t<nb)? bsum[t] : 0;
  buf[t]=v; __syncthreads();
  #pragma unroll
  for (int ofs=1; ofs<1024; ofs<<=1){
    int x=(t>=ofs)?buf[t-ofs]:0; __syncthreads(); buf[t]+=x; __syncthreads();
  }
  if (t<nb) bsum[t] = buf[t]-v;
  if (t==1023) off[n] = buf[1023];
}

__global__ __launch_bounds__(256) void k_scan_c(int* __restrict__ off, const int* __restrict__ bsum, int n){
  int i = blockIdx.x*256+threadIdx.x;
  if (i<n) off[i] += bsum[blockIdx.x];
}

__global__ __launch_bounds__(256) void k_scatter2(const int* __restrict__ di, const int* __restrict__ si,
    const int* __restrict__ off, int* __restrict__ cnt, int* __restrict__ sid){
  int i = blockIdx.x*256+threadIdx.x;
  if (i<EINT){
    int a = di[i];         sid[off[a]+atomicAdd(&cnt[a],1)] = si[i];
    int b = NITEMS+si[i];  sid[off[b]+atomicAdd(&cnt[b],1)] = di[i];
  }
}

// edge softmax weights: aw[pos][h] = a_e^h (bf16). thread = (node u in [0,2N), head h)
__global__ __launch_bounds__(256) void k_aw(const int* __restrict__ off, const int* __restrict__ sid,
    const float* __restrict__ ecat, u16* __restrict__ aw){
  int gt = blockIdx.x*256 + threadIdx.x;
  int u = gt >> 3, h = gt & 7;
  if (u >= 2*NITEMS) return;
  int g = (u >= NITEMS) ? 1 : 0;
  int w = u - g*NITEMS;
  int cl = g*16 + h, cr = g*16 + 8 + h;
  float ern = ecat[(size_t)w*32 + cr];
  int lo = off[u], hi = off[u+1];
  if (lo >= hi) return;
  float mh = -1e30f;
  for (int i=lo;i<hi;++i){
    float lv = ecat[(size_t)sid[i]*32 + cl] + ern;
    lv = (lv>=0.f)? lv : NEG_SLOPE*lv;
    mh = fmaxf(mh, lv);
  }
  float den = 0.f;
  for (int i=lo;i<hi;++i){
    float lv = ecat[(size_t)sid[i]*32 + cl] + ern;
    lv = (lv>=0.f)? lv : NEG_SLOPE*lv;
    den += expf(lv - mh);
  }
  float inv = 1.f/den;
  for (int i=lo;i<hi;++i){
    float lv = ecat[(size_t)sid[i]*32 + cl] + ern;
    lv = (lv>=0.f)? lv : NEG_SLOPE*lv;
    aw[(size_t)i*8 + h] = f2bf(expf(lv - mh)*inv);
  }
}

// Fused GAT: per block 128 nodes, 8 waves. Per head: build agg tile in LDS (weighted hvb
// gathers), then 128x128x128 MFMA GEMM vs fc_h (XOR-swizzled LDS), fold bias+head-max.
// MODE 0: h1 = max + hv.  MODE 1: h = normalize(h1 + max + hv) -> h1 (f32) + hb (bf16).
template<int MODE>
__global__ __launch_bounds__(512) void k_gat(const int* __restrict__ off, const int* __restrict__ sid,
    const u16* __restrict__ aw, const u16* __restrict__ hvb, const u16* __restrict__ wfc,
    const float* __restrict__ bias, const float* __restrict__ hv, float* __restrict__ h1,
    u16* __restrict__ hb, int obase){
  __shared__ u16 S[2*128*128];       // As = S[0:16384), Bs = S[16384:)
  __shared__ float rinv[128];
  u16* As = S;
  u16* Bs = S + 128*128;
  int n0 = blockIdx.x*128;
  int t = threadIdx.x, lane = t&63, wid = t>>6;
  int lr = lane&15, lq = lane>>4;    // lq 0..3
  int wm = wid>>1, wn = wid&1;       // wave tile: rows wm*32..+32, cols wn*64..+64
  // hoist per-node CSR ranges (head-invariant): this lane serves nodes wid*16 + cn*4 + lq
  int nlo[4], nhi[4];
  #pragma unroll
  for (int cn=0; cn<4; ++cn){
    int u = obase + n0 + wid*16 + cn*4 + lq;
    nlo[cn] = off[u]; nhi[cn] = off[u+1];
  }
  float rm[2][4][4];
  #pragma unroll
  for (int m=0;m<2;m++)
    #pragma unroll
    for (int n=0;n<4;n++)
      #pragma unroll
      for (int r=0;r<4;r++) rm[m][n][r] = -1e30f;

  for (int h=0; h<HN; ++h){
    __syncthreads();                 // previous head's LDS reads done
    // stage Bs = fc_h [128 x 128], XOR-swizzled
    #pragma unroll
    for (int i=0;i<4;++i){
      int c = t + i*512; int row = c>>4, cc = c&15;
      *(bf16x8*)(void*)&Bs[row*128 + ((cc ^ (row&7))*8)] =
        *(const bf16x8*)(const void*)&wfc[(size_t)(h*DD+row)*DD + cc*8];
    }
    // build As rows (agg_h): wave handles 16 nodes, 4 concurrent (sub=lq), lane covers dims lr*8..+8
    #pragma unroll
    for (int cn=0; cn<4; ++cn){
      int n = wid*16 + cn*4 + lq;
      float a[8] = {0.f,0.f,0.f,0.f,0.f,0.f,0.f,0.f};
      for (int i=nlo[cn]; i<nhi[cn]; ++i){
        float wt = bf2f(aw[(size_t)i*8 + h]);
        int s = sid[i];
        bf16x8 v = *(const bf16x8*)(const void*)&hvb[(size_t)s*DD + lr*8];
        #pragma unroll
        for (int j=0;j<8;j++) a[j] += wt * bf2f((u16)v[j]);
      }
      bf16x8 o;
      #pragma unroll
      for (int j=0;j<8;j++) o[j] = (short)f2bf(a[j]);
      *(bf16x8*)(void*)&As[n*128 + ((lr ^ (n&7))*8)] = o;
    }
    __syncthreads();
    f32x4 zero = {0.f,0.f,0.f,0.f};
    f32x4 acc[2][4];
    #pragma unroll
    for (int m=0;m<2;m++)
      #pragma unroll
      for (int n=0;n<4;n++) acc[m][n] = zero;
    #pragma unroll
    for (int ks=0; ks<4; ++ks){
      int cck = ks*4 + lq;
      bf16x8 af[2], bfr[4];
      #pragma unroll
      for (int m=0;m<2;m++){
        int row = wm*32 + m*16 + lr;
        af[m] = *(const bf16x8*)(const void*)&As[row*128 + ((cck ^ (row&7))*8)];
      }
      #pragma unroll
      for (int n=0;n<4;n++){
        int row = wn*64 + n*16 + lr;
        bfr[n] = *(const bf16x8*)(const void*)&Bs[row*128 + ((cck ^ (row&7))*8)];
      }
      #pragma unroll
      for (int m=0;m<2;m++)
        #pragma unroll
        for (int n=0;n<4;n++)
          acc[m][n] = __builtin_amdgcn_mfma_f32_16x16x32_bf16(af[m], bfr[n], acc[m][n], 0,0,0);
    }
    #pragma unroll
    for (int n=0;n<4;n++){
      float bn = bias[h*DD + wn*64 + n*16 + lr];
      #pragma unroll
      for (int m=0;m<2;m++)
        #pragma unroll
        for (int r=0;r<4;r++)
          rm[m][n][r] = fmaxf(rm[m][n][r], acc[m][n][r] + bn);
    }
  }
  // epilogue
  if (MODE==0){
    #pragma unroll
    for (int m=0;m<2;m++)
      #pragma unroll
      for (int n=0;n<4;n++)
        #pragma unroll
        for (int r=0;r<4;r++){
          int grow = n0 + wm*32 + m*16 + lq*4 + r;
          int col = wn*64 + n*16 + lr;
          h1[(size_t)grow*DD + col] = rm[m][n][r] + hv[(size_t)grow*DD + col];
        }
  } else {
    __syncthreads();
    float* F = (float*)S;            // 128x128 f32 tile (64 KB)
    #pragma unroll
    for (int m=0;m<2;m++)
      #pragma unroll
      for (int n=0;n<4;n++)
        #pragma unroll
        for (int r=0;r<4;r++){
          int lrow = wm*32 + m*16 + lq*4 + r;
          int col = wn*64 + n*16 + lr;
          int grow = n0 + lrow;
          F[lrow*DD + col] = rm[m][n][r] + hv[(size_t)grow*DD + col] + h1[(size_t)grow*DD + col];
        }
    __syncthreads();
    if (t < 128){
      float ss = 0.f;
      for (int j=0;j<DD;++j){
        int k = (t+j)&127;
        float x = F[t*DD + k];
        ss += x*x;
      }
      rinv[t] = 1.f/fmaxf(sqrtf(ss),1e-12f);
    }
    __syncthreads();
    #pragma unroll
    for (int i=0;i<32;++i){
      int idx = t + i*512;
      int row = idx>>7, col = idx&127;
      float o = F[idx]*rinv[row];
      h1[(size_t)(n0+row)*DD + col] = o;
      hb[(size_t)(n0+row)*DD + col] = f2bf(o);
    }
  }
}

// cat[i] = [ hb[agg_src[i]] | f2bf(pos_emb[pid[i]]) ]  (bf16, [EAGG,256]); 4 elems/thread
__global__ __launch_bounds__(256) void k_cat(const u16* __restrict__ hb, const float* __restrict__ pemb,
    const int* __restrict__ pid, const int* __restrict__ asrc, u16* __restrict__ cat){
  int idx = blockIdx.x*256 + threadIdx.x;
  if (idx >= EAGG*32) return;
  int i = idx >> 5;
  int c = (idx & 31) * 4;
  int s = asrc[i], p = pid[i];
  *(u16x4*)(void*)(cat + (size_t)i*256 + c) = *(const u16x4*)(const void*)(hb + (size_t)s*DD + c);
  float4 b = *(const float4*)(pemb + (size_t)p*DD + c);
  u16x4 ob = {f2bf(b.x),f2bf(b.y),f2bf(b.z),f2bf(b.w)};
  *(u16x4*)(void*)(cat + (size_t)i*256 + DD + c) = ob;
}

// w[i] = sum_j tanh(ep[i,j]) * target_emb[tid[agg_dst[i]], j]   (ep bf16)
__global__ __launch_bounds__(256) void k_w(const u16* __restrict__ ep, const int* __restrict__ adst,
    const int* __restrict__ tid_, const float* __restrict__ temb, float* __restrict__ w){
  int i = (blockIdx.x*256 + threadIdx.x) >> 6;
  int lane = threadIdx.x & 63;
  if (i >= EAGG) return;
  int t = adst[i];
  int tt = tid_[t];
  unsigned v = *(const unsigned*)(const void*)(ep + (size_t)i*DD + lane*2);
  float e0 = tanhf(bf2f((u16)(v&0xffffu)));
  float e1 = tanhf(bf2f((u16)(v>>16)));
  float2 te = *(const float2*)(temb + (size_t)tt*DD + lane*2);
  float s = e0*te.x + e1*te.y;
  #pragma unroll
  for (int m=1;m<64;m<<=1) s += __shfl_xor(s,m);
  if (lane==0) w[i] = s;
}

__device__ __forceinline__ int lbound(const int* a, int n, int key){
  int lo=0, hi=n;
  while (lo<hi){ int mid=(lo+hi)>>1; if (a[mid]<key) lo=mid+1; else hi=mid; }
  return lo;
}

// per-target: sr_g (segment sum over sorted agg_dst), concat with h[last], matmul fc_sr, normalize -> nsr bf16
__global__ __launch_bounds__(256) void k_sr(const float* __restrict__ h, const float* __restrict__ w,
    const int* __restrict__ asrc, const int* __restrict__ adst, const int* __restrict__ lastn,
    const float* __restrict__ fcsr, u16* __restrict__ nsr){
  __shared__ float cat[256];
  __shared__ float red[128];
  __shared__ int lohi[2];
  int t = blockIdx.x, tid = threadIdx.x;
  if (tid == 0){ lohi[0] = lbound(adst, EAGG, t); lohi[1] = lbound(adst, EAGG, t+1); }
  __syncthreads();
  int lo = lohi[0], hi = lohi[1];
  if (tid < DD){
    float a = 0.f;
    for (int i=lo;i<hi;++i) a += h[(size_t)asrc[i]*DD + tid] * w[i];
    cat[tid] = a;
  } else {
    int d = tid - DD;
    cat[DD + d] = h[(size_t)lastn[t]*DD + d];
  }
  __syncthreads();
  float s = 0.f;
  if (tid < DD){
    const float* row = fcsr + (size_t)tid*256;
    #pragma unroll 8
    for (int k=0;k<256;++k) s += cat[k]*row[k];
    red[tid] = s*s;
  }
  __syncthreads();
  for (int st=64; st>0; st>>=1){
    if (tid < st) red[tid] += red[tid+st];
    __syncthreads();
  }
  if (tid < DD){
    float inv = 1.f/fmaxf(sqrtf(red[0]),1e-12f);
    nsr[(size_t)t*DD + tid] = f2bf(s*inv);
  }
}

extern "C" void kernel_launch(void* const* d_in, const int* in_sizes, int n_in,
                              void* d_out, int out_size, void* d_ws, size_t ws_size,
                              hipStream_t stream){
  (void)in_sizes; (void)n_in; (void)out_size; (void)ws_size;
  const int*   iid   = (const int*)d_in[0];
  const int*   tid_  = (const int*)d_in[1];
  const int*   pid   = (const int*)d_in[2];
  const int*   src_i = (const int*)d_in[3];
  const int*   dst_i = (const int*)d_in[4];
  const int*   asrc  = (const int*)d_in[5];
  const int*   adst  = (const int*)d_in[6];
  const int*   lastn = (const int*)d_in[7];
  const float* emb   = (const float*)d_in[8];
  const float* pemb  = (const float*)d_in[9];
  const float* temb  = (const float*)d_in[10];
  const float* fc1   = (const float*)d_in[11];
  const float* al1   = (const float*)d_in[12];
  const float* ar1   = (const float*)d_in[13];
  const float* b1    = (const float*)d_in[14];
  const float* fc2   = (const float*)d_in[15];
  const float* al2   = (const float*)d_in[16];
  const float* ar2   = (const float*)d_in[17];
  const float* b2    = (const float*)d_in[18];
  const float* qw    = (const float*)d_in[19];
  const float* fcsr  = (const float*)d_in[20];

  char* ws = (char*)d_ws;
  size_t o = 0;
  auto alc = [&](size_t b)->char*{ char* r = ws + o; o += (b + 511) & ~(size_t)511; return r; };
  float* hv   = (float*)alc((size_t)NITEMS*DD*4);      // 42 MB
  u16*   hvb  = (u16*)  alc((size_t)NITEMS*DD*2);      // 21 MB
  float* h1   = (float*)alc((size_t)NITEMS*DD*4);      // 42 MB (h1, then normalized h in place)
  u16*   hb   = (u16*)  alc((size_t)NITEMS*DD*2);      // 21 MB (normalized h, bf16)
  float* ecat = (float*)alc((size_t)NITEMS*32*4);      // 10.5 MB (el1|er1|el2|er2)
  int*   off  = (int*)  alc((size_t)(2*NITEMS+1)*4);
  int*   cnt  = (int*)  alc((size_t)(2*NITEMS)*4);
  int*   bsum = (int*)  alc((size_t)1024*4);
  int*   sid  = (int*)  alc((size_t)(2*EINT)*4);       // other-endpoint per CSR slot
  u16*   aw   = (u16*)  alc((size_t)(2*EINT)*8*2);     // 5.2 MB edge softmax weights
  u16*   wfc1 = (u16*)  alc((size_t)1024*DD*2);
  u16*   wfc2 = (u16*)  alc((size_t)1024*DD*2);
  u16*   qwb  = (u16*)  alc((size_t)DD*256*2);
  u16*   Umat = (u16*)  alc((size_t)128*DD*2);
  float* wv   = (float*)alc((size_t)EAGG*4);
  u16*   nsr  = (u16*)  alc((size_t)NT*DD*2);
  u16*   nemb = (u16*)  alc((size_t)NVPAD*DD*2);       // 10.3 MB
  u16*   catb = (u16*)  alc((size_t)EAGG*256*2);       // 42 MB
  u16*   epb  = (u16*)  alc((size_t)EAGG*DD*2);        // 21 MB

  const int N2 = 2*NITEMS;
  const int NB2 = N2/256;    // 640

  // ---- precompute ----
  hipMemsetAsync(Umat, 0, (size_t)128*DD*2, stream);
  k_prep_u<<<8, 128, 0, stream>>>(fc1, al1, ar1, fc2, al2, ar2, Umat);
  k_hv  <<<NITEMS/4, 256, 0, stream>>>(emb, iid, hv, hvb, NITEMS);
  k_nemb<<<NVPAD/4,  256, 0, stream>>>(emb, nemb);
  k_cast<<<512, 256, 0, stream>>>(fc1, wfc1, 1024*DD);
  k_cast<<<512, 256, 0, stream>>>(fc2, wfc2, 1024*DD);
  k_cast<<<128, 256, 0, stream>>>(qw, qwb, DD*256);
  gemm_nt<0><<<dim3(NITEMS/128, 1), 256, 0, stream>>>(hvb, Umat, ecat, NITEMS, 128, DD, 1.f, 32, 32);

  // ---- combined CSR ----
  hipMemsetAsync(cnt, 0, (size_t)N2*4, stream);
  k_deg2<<<(EINT+255)/256, 256, 0, stream>>>(dst_i, src_i, cnt);
  k_scan_a<<<NB2, 256, 0, stream>>>(cnt, off, bsum, N2);
  k_scan_b<<<1, 1024, 0, stream>>>(bsum, off, NB2, N2);
  k_scan_c<<<NB2, 256, 0, stream>>>(off, bsum, N2);
  k_scatter2<<<(EINT+255)/256, 256, 0, stream>>>(dst_i, src_i, off, cnt, sid);

  // ---- edge softmax weights (both graphs, all heads) ----
  k_aw<<<(N2*8)/256, 256, 0, stream>>>(off, sid, ecat, aw);

  // ---- fused GAT (agg-in-LDS + per-head GEMM + bias + head-max + residual) ----
  k_gat<0><<<NITEMS/128, 512, 0, stream>>>(off, sid, aw, hvb, wfc1, b1, hv, h1, nullptr, 0);
  k_gat<1><<<NITEMS/128, 512, 0, stream>>>(off, sid, aw, hvb, wfc2, b2, hv, h1, hb, NITEMS);

  // ---- PosAggregator ----
  k_cat<<<(EAGG*32)/256, 256, 0, stream>>>(hb, pemb, pid, asrc, catb);
  gemm_nt<1><<<dim3(EAGG/128, 1), 256, 0, stream>>>(catb, qwb, epb, EAGG, 128, 256, 1.f, 128, 128);
  k_w<<<EAGG/4, 256, 0, stream>>>(epb, adst, tid_, temb, wv);
  k_sr<<<NT, 256, 0, stream>>>(h1, wv, asrc, adst, lastn, fcsr, nsr);

  // ---- scores = SCALE * nsr @ nemb^T ----
  gemm_nt<0><<<dim3(NT/128, NVPAD/128), 256, 0, stream>>>(nsr, nemb, (float*)d_out, NT, NVPAD, DD, SCALE, NV, NV);
}

// Round 5
// 796.812 us; speedup vs baseline: 1.2918x; 1.0447x over previous
//
#include <hip/hip_runtime.h>
#include <stdint.h>

#define DD 128
#define HN 8
#define NITEMS 81920
#define EINT 163840
#define NT 4096
#define NV 40000
#define NVPAD 40064
#define EAGG 81920
#define NEG_SLOPE 0.2f
#define SCALE 12.0f

typedef unsigned short u16;
typedef __attribute__((ext_vector_type(8))) short bf16x8;
typedef __attribute__((ext_vector_type(4))) float f32x4;
typedef __attribute__((ext_vector_type(4))) unsigned short u16x4;

__device__ __forceinline__ float bf2f(unsigned short u){ return __uint_as_float(((unsigned)u)<<16); }
__device__ __forceinline__ unsigned short f2bf(float f){
  unsigned u = __float_as_uint(f);
  u += 0x7fffu + ((u>>16)&1u);
  return (unsigned short)(u>>16);
}

// fc1|fc2|qw -> bf16 in one launch
__global__ __launch_bounds__(256) void k_cast3(const float* __restrict__ fc1, const float* __restrict__ fc2,
    const float* __restrict__ qw, u16* __restrict__ w1, u16* __restrict__ w2, u16* __restrict__ qb){
  int i = blockIdx.x*256 + threadIdx.x;
  if (i < 131072) w1[i] = f2bf(fc1[i]);
  else if (i < 262144) w2[i-131072] = f2bf(fc2[i-131072]);
  else if (i < 294912) qb[i-262144] = f2bf(qw[i-262144]);
}

// U[r][k]: r = g*8+h (g: 0=l1,1=r1,2=l2,3=r2), rows 32..127 zero
__global__ __launch_bounds__(128) void k_prep_u(const float* __restrict__ fc1, const float* __restrict__ al1,
    const float* __restrict__ ar1, const float* __restrict__ fc2, const float* __restrict__ al2,
    const float* __restrict__ ar2, u16* __restrict__ U){
  int r = blockIdx.x, k = threadIdx.x;
  if (r >= 32){ U[(size_t)r*DD + k] = 0; return; }
  int g = r>>3, h = r&7;
  const float* fc = (g>=2)? fc2 : fc1;
  const float* av = (g==0)? al1 : (g==1)? ar1 : (g==2)? al2 : ar2;
  float s = 0.f;
  for (int d=0; d<DD; ++d) s += fc[(size_t)(h*DD+d)*DD + k] * av[h*DD+d];
  U[(size_t)r*DD + k] = f2bf(s);
}

// rows [0,NVPAD): nemb (normalized emb, bf16, pad=0); rows [NVPAD, +NITEMS): hvb = normalize(emb[iid]).
// Also zeroes cnt[0:2N).
__global__ __launch_bounds__(256) void k_norm(const float* __restrict__ emb, const int* __restrict__ iid,
    u16* __restrict__ nemb, u16* __restrict__ hvb, int* __restrict__ cnt){
  int gi = blockIdx.x*256 + threadIdx.x;
  if (gi < 2*NITEMS) cnt[gi] = 0;
  int w = gi >> 6;
  int lane = gi & 63;
  u16* dst; const float* src;
  if (w < NVPAD){
    dst = nemb + (size_t)w*DD;
    if (w >= NV){ dst[lane*2]=0; dst[lane*2+1]=0; return; }
    src = emb + (size_t)w*DD;
  } else {
    int n = w - NVPAD;
    dst = hvb + (size_t)n*DD;
    src = emb + (size_t)iid[n]*DD;
  }
  float2 v = *(const float2*)(src + lane*2);
  float ss = v.x*v.x + v.y*v.y;
  #pragma unroll
  for (int m=1;m<64;m<<=1) ss += __shfl_xor(ss, m);
  float inv = 1.f / fmaxf(sqrtf(ss), 1e-12f);
  dst[lane*2]   = f2bf(v.x*inv);
  dst[lane*2+1] = f2bf(v.y*inv);
}

// generic NT GEMM, 128x128 tile, K-step 32 (used for ecat)
template<int OUT_BF16>
__global__ __launch_bounds__(256) void gemm_nt(const u16* __restrict__ A, const u16* __restrict__ B,
                                               void* __restrict__ C, int M, int N, int K,
                                               float alpha, int ldc, int nvalid){
  __shared__ u16 As[128*32];
  __shared__ u16 Bs[128*32];
  int m0 = blockIdx.x*128, n0 = blockIdx.y*128;
  int t = threadIdx.x, lane = t&63, wid = t>>6;
  int wm = wid>>1, wn = wid&1;
  f32x4 zero = {0.f,0.f,0.f,0.f};
  f32x4 acc[4][4];
  #pragma unroll
  for (int i=0;i<4;i++)
    #pragma unroll
    for (int j=0;j<4;j++) acc[i][j] = zero;
  int lr = lane & 15, lk = (lane>>4)*8;
  for (int k0=0; k0<K; k0+=32){
    #pragma unroll
    for (int cc=0; cc<2; ++cc){
      int c = t + cc*256;
      int row = c>>2, col = (c&3)*8;
      *(bf16x8*)(void*)&As[c*8] = *(const bf16x8*)(const void*)&A[(size_t)(m0+row)*K + k0 + col];
      *(bf16x8*)(void*)&Bs[c*8] = *(const bf16x8*)(const void*)&B[(size_t)(n0+row)*K + k0 + col];
    }
    __syncthreads();
    bf16x8 af[4], bfr[4];
    #pragma unroll
    for (int m=0;m<4;m++) af[m]  = *(const bf16x8*)(const void*)&As[(wm*64+m*16+lr)*32 + lk];
    #pragma unroll
    for (int n=0;n<4;n++) bfr[n] = *(const bf16x8*)(const void*)&Bs[(wn*64+n*16+lr)*32 + lk];
    #pragma unroll
    for (int m=0;m<4;m++)
      #pragma unroll
      for (int n=0;n<4;n++)
        acc[m][n] = __builtin_amdgcn_mfma_f32_16x16x32_bf16(af[m], bfr[n], acc[m][n], 0,0,0);
    __syncthreads();
  }
  #pragma unroll
  for (int m=0;m<4;m++)
    #pragma unroll
    for (int n=0;n<4;n++)
      #pragma unroll
      for (int r=0;r<4;r++){
        int row = m0 + wm*64 + m*16 + (lane>>4)*4 + r;
        int col = n0 + wn*64 + n*16 + (lane&15);
        if (col < nvalid){
          float v = acc[m][n][r]*alpha;
          if (OUT_BF16) ((u16*)C)[(size_t)row*ldc + col] = f2bf(v);
          else          ((float*)C)[(size_t)row*ldc + col] = v;
        }
      }
}

// ---- combined CSR (keys: dst_i | NITEMS+src_i); sid stores the OTHER endpoint ----
__global__ __launch_bounds__(256) void k_deg2(const int* __restrict__ di, const int* __restrict__ si,
                                              int* __restrict__ cnt){
  int i = blockIdx.x*256+threadIdx.x;
  if (i<EINT){ atomicAdd(&cnt[di[i]],1); atomicAdd(&cnt[NITEMS+si[i]],1); }
}

__global__ __launch_bounds__(256) void k_scan_a(int* cnt, int* off, int* bsum, int n){
  __shared__ int buf[256];
  int b = blockIdx.x, t = threadIdx.x, i = b*256+t;
  int v = (i<n)? cnt[i] : 0;
  buf[t] = v; __syncthreads();
  #pragma unroll
  for (int ofs=1; ofs<256; ofs<<=1){
    int x = (t>=ofs)? buf[t-ofs] : 0;
    __syncthreads();
    buf[t] += x;
    __syncthreads();
  }
  if (i<n){ off[i] = buf[t]-v; cnt[i] = 0; }
  if (t==255) bsum[b] = buf[255];
}

__global__ __launch_bounds__(1024) void k_scan_b(int* bsum, int* off, int nb, int n){
  __shared__ int buf[1024];
  int t = threadIdx.x;
  int v = (t<nb)? bsum[t] : 0;
  buf[t]=v; __syncthreads();
  #pragma unroll
  for (int ofs=1; ofs<1024; ofs<<=1){
    int x=(t>=ofs)?buf[t-ofs]:0; __syncthreads(); buf[t]+=x; __syncthreads();
  }
  if (t<nb) bsum[t] = buf[t]-v;
  if (t==1023) off[n] = buf[1023];
}

__global__ __launch_bounds__(256) void k_scan_c(int* __restrict__ off, const int* __restrict__ bsum, int n){
  int i = blockIdx.x*256+threadIdx.x;
  if (i<n) off[i] += bsum[blockIdx.x];
}

__global__ __launch_bounds__(256) void k_scatter2(const int* __restrict__ di, const int* __restrict__ si,
    const int* __restrict__ off, int* __restrict__ cnt, int* __restrict__ sid){
  int i = blockIdx.x*256+threadIdx.x;
  if (i<EINT){
    int a = di[i];         sid[off[a]+atomicAdd(&cnt[a],1)] = si[i];
    int b = NITEMS+si[i];  sid[off[b]+atomicAdd(&cnt[b],1)] = di[i];
  }
}

// edge softmax weights, thread per node u in [0,2N), all 8 heads vectorized.
// No max-subtraction: |logit| <= ~3 so plain exp is safe and identical after normalization.
__global__ __launch_bounds__(256) void k_aw(const int* __restrict__ off, const int* __restrict__ sid,
    const float* __restrict__ ecat, u16* __restrict__ aw){
  int u = blockIdx.x*256 + threadIdx.x;
  if (u >= 2*NITEMS) return;
  int g = (u >= NITEMS) ? 1 : 0;
  int w = u - g*NITEMS;
  int cl = g*16, cr = g*16 + 8;
  float ern[8];
  #pragma unroll
  for (int h=0;h<8;h++) ern[h] = ecat[(size_t)w*32 + cr + h];
  int lo = off[u], hi = off[u+1];
  float den[8];
  #pragma unroll
  for (int h=0;h<8;h++) den[h] = 0.f;
  for (int i=lo;i<hi;++i){
    const float* e = ecat + (size_t)sid[i]*32 + cl;
    #pragma unroll
    for (int h=0;h<8;h++){
      float lv = e[h] + ern[h];
      lv = (lv>=0.f)? lv : NEG_SLOPE*lv;
      den[h] += expf(lv);
    }
  }
  float inv[8];
  #pragma unroll
  for (int h=0;h<8;h++) inv[h] = (den[h]>0.f)? 1.f/den[h] : 0.f;
  for (int i=lo;i<hi;++i){
    const float* e = ecat + (size_t)sid[i]*32 + cl;
    bf16x8 o;
    #pragma unroll
    for (int h=0;h<8;h++){
      float lv = e[h] + ern[h];
      lv = (lv>=0.f)? lv : NEG_SLOPE*lv;
      o[h] = (short)f2bf(expf(lv)*inv[h]);
    }
    *(bf16x8*)(void*)&aw[(size_t)i*8] = o;
  }
}

// Fully fused GAT (both graphs): block = 16 nodes, 256 threads (4 waves).
// Per graph: one pass over edges accumulates all 8 heads in registers (16 thr/node,
// a[8][8] each), staged to a 32KB XOR-swizzled LDS tile; per head a 16x128x128 MFMA
// vs fc_h (B-fragments straight from L2), bias+head-max folded. Epilogue:
// h = normalize(rm1 + rm2 + 2*hv) -> hb (bf16).
__global__ __launch_bounds__(256) void k_gatfuse(const int* __restrict__ off, const int* __restrict__ sid,
    const u16* __restrict__ aw, const u16* __restrict__ hvb,
    const u16* __restrict__ wfc1, const u16* __restrict__ wfc2,
    const float* __restrict__ b1, const float* __restrict__ b2,
    u16* __restrict__ hb){
  __shared__ u16 agg[8][16][128];
  __shared__ float nss[16];
  int n0 = blockIdx.x*16;
  int t = threadIdx.x, lane = t&63, wid = t>>6;
  int lr = lane&15, lq = lane>>4;
  if (t < 16) nss[t] = 0.f;
  float rm[2][2][4];
  #pragma unroll
  for (int g=0;g<2;g++)
    #pragma unroll
    for (int n=0;n<2;n++)
      #pragma unroll
      for (int r=0;r<4;r++) rm[g][n][r] = -1e30f;

  #pragma unroll
  for (int g=0; g<2; ++g){
    const u16* wfc = g ? wfc2 : wfc1;
    const float* bias = g ? b2 : b1;
    if (g) __syncthreads();          // protect agg reuse after g=0 MFMA reads
    // gather: thread (nd = t>>4, dch = t&15)
    {
      int nd = t>>4, dch = t&15;
      int u = g*NITEMS + n0 + nd;
      int lo = off[u], hi = off[u+1];
      float a[8][8];
      #pragma unroll
      for (int h=0;h<8;h++)
        #pragma unroll
        for (int j=0;j<8;j++) a[h][j] = 0.f;
      for (int i=lo; i<hi; ++i){
        int s = sid[i];
        bf16x8 v  = *(const bf16x8*)(const void*)&hvb[(size_t)s*DD + dch*8];
        bf16x8 w8 = *(const bf16x8*)(const void*)&aw[(size_t)i*8];
        float f[8];
        #pragma unroll
        for (int j=0;j<8;j++) f[j] = bf2f((u16)v[j]);
        #pragma unroll
        for (int h=0;h<8;h++){
          float wa = bf2f((u16)w8[h]);
          #pragma unroll
          for (int j=0;j<8;j++) a[h][j] += wa * f[j];
        }
      }
      #pragma unroll
      for (int h=0;h<8;h++){
        bf16x8 o;
        #pragma unroll
        for (int j=0;j<8;j++) o[j] = (short)f2bf(a[h][j]);
        *(bf16x8*)(void*)&agg[h][nd][((dch ^ (nd&7)))*8] = o;
      }
    }
    __syncthreads();
    // MFMA: wave covers output cols wid*32 .. +32 (2 col-frags)
    #pragma unroll
    for (int h=0; h<8; ++h){
      f32x4 acc0 = {0.f,0.f,0.f,0.f}, acc1 = {0.f,0.f,0.f,0.f};
      #pragma unroll
      for (int ks=0; ks<4; ++ks){
        int cA = (ks*4 + lq) ^ (lr&7);
        bf16x8 af = *(const bf16x8*)(const void*)&agg[h][lr][cA*8];
        int br0 = wid*32 + lr, br1 = wid*32 + 16 + lr;
        bf16x8 bf0 = *(const bf16x8*)(const void*)&wfc[(size_t)(h*DD + br0)*DD + ks*32 + lq*8];
        bf16x8 bf1 = *(const bf16x8*)(const void*)&wfc[(size_t)(h*DD + br1)*DD + ks*32 + lq*8];
        acc0 = __builtin_amdgcn_mfma_f32_16x16x32_bf16(af, bf0, acc0, 0,0,0);
        acc1 = __builtin_amdgcn_mfma_f32_16x16x32_bf16(af, bf1, acc1, 0,0,0);
      }
      float bn0 = bias[h*DD + wid*32 + lr];
      float bn1 = bias[h*DD + wid*32 + 16 + lr];
      #pragma unroll
      for (int r=0;r<4;r++){
        rm[g][0][r] = fmaxf(rm[g][0][r], acc0[r] + bn0);
        rm[g][1][r] = fmaxf(rm[g][1][r], acc1[r] + bn1);
      }
    }
  }
  // epilogue: tot = rm1 + rm2 + 2*hv; h = normalize(tot)
  float tot[2][4], ssp[4] = {0.f,0.f,0.f,0.f};
  #pragma unroll
  for (int n=0;n<2;n++)
    #pragma unroll
    for (int r=0;r<4;r++){
      int node = lq*4 + r;
      int col = wid*32 + n*16 + lr;
      float hvv = bf2f(hvb[(size_t)(n0+node)*DD + col]);
      float v = rm[0][n][r] + rm[1][n][r] + 2.f*hvv;
      tot[n][r] = v;
      ssp[r] += v*v;
    }
  #pragma unroll
  for (int m=1;m<16;m<<=1){
    #pragma unroll
    for (int r=0;r<4;r++) ssp[r] += __shfl_xor(ssp[r], m);
  }
  if (lr==0){
    #pragma unroll
    for (int r=0;r<4;r++) atomicAdd(&nss[lq*4+r], ssp[r]);
  }
  __syncthreads();
  #pragma unroll
  for (int r=0;r<4;r++){
    int node = lq*4 + r;
    float inv = 1.f/fmaxf(sqrtf(nss[node]),1e-12f);
    #pragma unroll
    for (int n=0;n<2;n++){
      int col = wid*32 + n*16 + lr;
      hb[(size_t)(n0+node)*DD + col] = f2bf(tot[n][r]*inv);
    }
  }
}

// ep GEMM with gathered A rows ([hb[asrc]|pemb[pid]] built in staging) and fused
// w-epilogue: w[i] = sum_j tanh(ep[i,j]) * temb[tid[adst[i]], j]. Writes only wv.
__global__ __launch_bounds__(256) void k_epw(const int* __restrict__ asrc, const int* __restrict__ pid,
    const int* __restrict__ adst, const int* __restrict__ tid_, const u16* __restrict__ hb,
    const float* __restrict__ pemb, const u16* __restrict__ qwb, const float* __restrict__ temb,
    float* __restrict__ wv){
  __shared__ u16 As[128*32];
  __shared__ u16 Bs[128*32];
  __shared__ float tembS[10*DD];
  __shared__ float wsum[128];
  __shared__ int rowtt[128];
  int m0 = blockIdx.x*128;
  int t = threadIdx.x, lane = t&63, wid = t>>6;
  int wm = wid>>1, wn = wid&1, lr = lane&15, lq = lane>>4;
  for (int i=t; i<10*DD; i+=256) tembS[i] = temb[i];
  if (t < 128){ rowtt[t] = tid_[adst[m0+t]]; wsum[t] = 0.f; }
  f32x4 zero = {0.f,0.f,0.f,0.f};
  f32x4 acc[4][4];
  #pragma unroll
  for (int i=0;i<4;i++)
    #pragma unroll
    for (int j=0;j<4;j++) acc[i][j] = zero;
  for (int k0=0; k0<256; k0+=32){
    #pragma unroll
    for (int cc=0; cc<2; ++cc){
      int c = t + cc*256;
      int row = c>>2;
      int kk = k0 + (c&3)*8;
      bf16x8 av;
      if (k0 < 128){
        av = *(const bf16x8*)(const void*)&hb[(size_t)asrc[m0+row]*DD + kk];
      } else {
        const float* p = pemb + (size_t)pid[m0+row]*DD + (kk-128);
        float4 p0 = *(const float4*)p;
        float4 p1 = *(const float4*)(p+4);
        av[0]=(short)f2bf(p0.x); av[1]=(short)f2bf(p0.y); av[2]=(short)f2bf(p0.z); av[3]=(short)f2bf(p0.w);
        av[4]=(short)f2bf(p1.x); av[5]=(short)f2bf(p1.y); av[6]=(short)f2bf(p1.z); av[7]=(short)f2bf(p1.w);
      }
      *(bf16x8*)(void*)&As[c*8] = av;
      *(bf16x8*)(void*)&Bs[c*8] = *(const bf16x8*)(const void*)&qwb[(size_t)row*256 + kk];
    }
    __syncthreads();
    bf16x8 af[4], bfr[4];
    #pragma unroll
    for (int m=0;m<4;m++) af[m]  = *(const bf16x8*)(const void*)&As[(wm*64+m*16+lr)*32 + lq*8];
    #pragma unroll
    for (int n=0;n<4;n++) bfr[n] = *(const bf16x8*)(const void*)&Bs[(wn*64+n*16+lr)*32 + lq*8];
    #pragma unroll
    for (int m=0;m<4;m++)
      #pragma unroll
      for (int n=0;n<4;n++)
        acc[m][n] = __builtin_amdgcn_mfma_f32_16x16x32_bf16(af[m], bfr[n], acc[m][n], 0,0,0);
    __syncthreads();
  }
  // epilogue: per-row weighted tanh reduction
  #pragma unroll
  for (int m=0;m<4;m++)
    #pragma unroll
    for (int r=0;r<4;r++){
      int lrow = wm*64 + m*16 + lq*4 + r;
      int tt = rowtt[lrow];
      float p = 0.f;
      #pragma unroll
      for (int n=0;n<4;n++){
        int col = wn*64 + n*16 + lr;
        p += tanhf(acc[m][n][r]) * tembS[tt*DD + col];
      }
      #pragma unroll
      for (int msk=1; msk<16; msk<<=1) p += __shfl_xor(p, msk);
      if (lr==0) atomicAdd(&wsum[lrow], p);
    }
  __syncthreads();
  if (t < 128) wv[m0+t] = wsum[t];
}

__device__ __forceinline__ int lbound(const int* a, int n, int key){
  int lo=0, hi=n;
  while (lo<hi){ int mid=(lo+hi)>>1; if (a[mid]<key) lo=mid+1; else hi=mid; }
  return lo;
}

// per-target: sr_g segment sum (hb rows, f32 accum), concat h[last], fc_sr matvec, normalize -> nsr bf16
__global__ __launch_bounds__(256) void k_sr(const u16* __restrict__ hb, const float* __restrict__ w,
    const int* __restrict__ asrc, const int* __restrict__ adst, const int* __restrict__ lastn,
    const float* __restrict__ fcsr, u16* __restrict__ nsr){
  __shared__ float cat[256];
  __shared__ float red[128];
  __shared__ int lohi[2];
  int t = blockIdx.x, tid = threadIdx.x;
  if (tid == 0){ lohi[0] = lbound(adst, EAGG, t); lohi[1] = lbound(adst, EAGG, t+1); }
  __syncthreads();
  int lo = lohi[0], hi = lohi[1];
  if (tid < DD){
    float a = 0.f;
    for (int i=lo;i<hi;++i) a += bf2f(hb[(size_t)asrc[i]*DD + tid]) * w[i];
    cat[tid] = a;
  } else {
    int d = tid - DD;
    cat[DD + d] = bf2f(hb[(size_t)lastn[t]*DD + d]);
  }
  __syncthreads();
  float s = 0.f;
  if (tid < DD){
    const float* row = fcsr + (size_t)tid*256;
    #pragma unroll 8
    for (int k=0;k<256;++k) s += cat[k]*row[k];
    red[tid] = s*s;
  }
  __syncthreads();
  for (int st=64; st>0; st>>=1){
    if (tid < st) red[tid] += red[tid+st];
    __syncthreads();
  }
  if (tid < DD){
    float inv = 1.f/fmaxf(sqrtf(red[0]),1e-12f);
    nsr[(size_t)t*DD + tid] = f2bf(s*inv);
  }
}

// scores GEMM: K=128 (4 steps), XCD-chunked swizzle, LDS-transpose epilogue (dwordx4 stores)
__global__ __launch_bounds__(256) void gemm_sc(const u16* __restrict__ A, const u16* __restrict__ B,
                                               float* __restrict__ C){
  __shared__ __align__(16) char smem[16384];
  u16* As = (u16*)smem;            // [128*32]
  u16* Bs = As + 4096;             // [128*32]
  float* tr = (float*)smem;        // 4096 f32, reused after K-loop
  int flat = blockIdx.y*gridDim.x + blockIdx.x;     // 10016 = 8*1252, x fastest
  int nf = (flat&7)*1252 + (flat>>3);
  int m0 = (nf & 31)*128;
  int n0 = (nf >> 5)*128;
  int t = threadIdx.x, lane = t&63, wid = t>>6;
  int wm = wid>>1, wn = wid&1, lr = lane&15, lq = lane>>4;
  f32x4 zero = {0.f,0.f,0.f,0.f};
  f32x4 acc[4][4];
  #pragma unroll
  for (int i=0;i<4;i++)
    #pragma unroll
    for (int j=0;j<4;j++) acc[i][j] = zero;
  for (int k0=0; k0<DD; k0+=32){
    #pragma unroll
    for (int cc=0; cc<2; ++cc){
      int c = t + cc*256;
      int row = c>>2, col = (c&3)*8;
      *(bf16x8*)(void*)&As[c*8] = *(const bf16x8*)(const void*)&A[(size_t)(m0+row)*DD + k0 + col];
      *(bf16x8*)(void*)&Bs[c*8] = *(const bf16x8*)(const void*)&B[(size_t)(n0+row)*DD + k0 + col];
    }
    __syncthreads();
    bf16x8 af[4], bfr[4];
    #pragma unroll
    for (int m=0;m<4;m++) af[m]  = *(const bf16x8*)(const void*)&As[(wm*64+m*16+lr)*32 + lq*8];
    #pragma unroll
    for (int n=0;n<4;n++) bfr[n] = *(const bf16x8*)(const void*)&Bs[(wn*64+n*16+lr)*32 + lq*8];
    #pragma unroll
    for (int m=0;m<4;m++)
      #pragma unroll
      for (int n=0;n<4;n++)
        acc[m][n] = __builtin_amdgcn_mfma_f32_16x16x32_bf16(af[m], bfr[n], acc[m][n], 0,0,0);
    __syncthreads();
  }
  // transpose-in-LDS epilogue: per m-chunk, wave tile 16 rows x 64 cols -> dwordx4 stores
  #pragma unroll
  for (int m=0;m<4;m++){
    #pragma unroll
    for (int n=0;n<4;n++)
      #pragma unroll
      for (int r=0;r<4;r++)
        tr[wid*1024 + (lq*4+r)*64 + n*16 + lr] = acc[m][n][r]*SCALE;
    __syncthreads();
    int row16 = lane>>2, ch = (lane&3)*16;
    int grow = m0 + wm*64 + m*16 + row16;
    int gcol = n0 + wn*64 + ch;
    if (gcol < NV){
      const float* s = &tr[wid*1024 + row16*64 + ch];
      float* d = &C[(size_t)grow*NV + gcol];
      *(float4*)(d)    = *(const float4*)(s);
      *(float4*)(d+4)  = *(const float4*)(s+4);
      *(float4*)(d+8)  = *(const float4*)(s+8);
      *(float4*)(d+12) = *(const float4*)(s+12);
    }
    __syncthreads();
  }
}

extern "C" void kernel_launch(void* const* d_in, const int* in_sizes, int n_in,
                              void* d_out, int out_size, void* d_ws, size_t ws_size,
                              hipStream_t stream){
  (void)in_sizes; (void)n_in; (void)out_size; (void)ws_size;
  const int*   iid   = (const int*)d_in[0];
  const int*   tid_  = (const int*)d_in[1];
  const int*   pid   = (const int*)d_in[2];
  const int*   src_i = (const int*)d_in[3];
  const int*   dst_i = (const int*)d_in[4];
  const int*   asrc  = (const int*)d_in[5];
  const int*   adst  = (const int*)d_in[6];
  const int*   lastn = (const int*)d_in[7];
  const float* emb   = (const float*)d_in[8];
  const float* pemb  = (const float*)d_in[9];
  const float* temb  = (const float*)d_in[10];
  const float* fc1   = (const float*)d_in[11];
  const float* al1   = (const float*)d_in[12];
  const float* ar1   = (const float*)d_in[13];
  const float* b1    = (const float*)d_in[14];
  const float* fc2   = (const float*)d_in[15];
  const float* al2   = (const float*)d_in[16];
  const float* ar2   = (const float*)d_in[17];
  const float* b2    = (const float*)d_in[18];
  const float* qw    = (const float*)d_in[19];
  const float* fcsr  = (const float*)d_in[20];

  char* ws = (char*)d_ws;
  size_t o = 0;
  auto alc = [&](size_t b)->char*{ char* r = ws + o; o += (b + 511) & ~(size_t)511; return r; };
  u16*   hvb  = (u16*)  alc((size_t)NITEMS*DD*2);      // 21 MB
  u16*   hb   = (u16*)  alc((size_t)NITEMS*DD*2);      // 21 MB
  float* ecat = (float*)alc((size_t)NITEMS*32*4);      // 10.5 MB (el1|er1|el2|er2)
  int*   off  = (int*)  alc((size_t)(2*NITEMS+1)*4);
  int*   cnt  = (int*)  alc((size_t)(2*NITEMS)*4);
  int*   bsum = (int*)  alc((size_t)1024*4);
  int*   sid  = (int*)  alc((size_t)(2*EINT)*4);       // 1.3 MB
  u16*   aw   = (u16*)  alc((size_t)(2*EINT)*8*2);     // 5.2 MB
  u16*   wfc1 = (u16*)  alc((size_t)1024*DD*2);
  u16*   wfc2 = (u16*)  alc((size_t)1024*DD*2);
  u16*   qwb  = (u16*)  alc((size_t)DD*256*2);
  u16*   Umat = (u16*)  alc((size_t)128*DD*2);
  float* wv   = (float*)alc((size_t)EAGG*4);
  u16*   nsr  = (u16*)  alc((size_t)NT*DD*2);
  u16*   nemb = (u16*)  alc((size_t)NVPAD*DD*2);       // 10.3 MB

  const int N2 = 2*NITEMS;
  const int NB2 = N2/256;    // 640

  // prep (also zeroes cnt)
  k_norm<<<(NVPAD+NITEMS)/4, 256, 0, stream>>>(emb, iid, nemb, hvb, cnt);
  k_prep_u<<<128, 128, 0, stream>>>(fc1, al1, ar1, fc2, al2, ar2, Umat);
  k_cast3<<<(294912)/256, 256, 0, stream>>>(fc1, fc2, qw, wfc1, wfc2, qwb);
  gemm_nt<0><<<dim3(NITEMS/128, 1), 256, 0, stream>>>(hvb, Umat, ecat, NITEMS, 128, DD, 1.f, 32, 32);

  // combined CSR
  k_deg2<<<(EINT+255)/256, 256, 0, stream>>>(dst_i, src_i, cnt);
  k_scan_a<<<NB2, 256, 0, stream>>>(cnt, off, bsum, N2);
  k_scan_b<<<1, 1024, 0, stream>>>(bsum, off, NB2, N2);
  k_scan_c<<<NB2, 256, 0, stream>>>(off, bsum, N2);
  k_scatter2<<<(EINT+255)/256, 256, 0, stream>>>(dst_i, src_i, off, cnt, sid);

  // edge softmax weights (both graphs, all heads)
  k_aw<<<N2/256, 256, 0, stream>>>(off, sid, ecat, aw);

  // fused double-GAT -> hb
  k_gatfuse<<<NITEMS/16, 256, 0, stream>>>(off, sid, aw, hvb, wfc1, wfc2, b1, b2, hb);

  // PosAggregator: ep GEMM with gathered A + fused w epilogue
  k_epw<<<EAGG/128, 256, 0, stream>>>(asrc, pid, adst, tid_, hb, pemb, qwb, temb, wv);
  k_sr<<<NT, 256, 0, stream>>>(hb, wv, asrc, adst, lastn, fcsr, nsr);

  // scores
  gemm_sc<<<dim3(32, NVPAD/128), 256, 0, stream>>>(nsr, nemb, (float*)d_out);
}

// Round 6
// 674.340 us; speedup vs baseline: 1.5264x; 1.1816x over previous
//
#include <hip/hip_runtime.h>
#include <stdint.h>

#define DD 128
#define HN 8
#define NITEMS 81920
#define EINT 163840
#define NT 4096
#define NV 40000
#define NVPAD 40064
#define EAGG 81920
#define NEG_SLOPE 0.2f
#define SCALE 12.0f

typedef unsigned short u16;
typedef __attribute__((ext_vector_type(8))) short bf16x8;
typedef __attribute__((ext_vector_type(4))) float f32x4;
typedef __attribute__((ext_vector_type(4))) unsigned short u16x4;

__device__ __forceinline__ float bf2f(unsigned short u){ return __uint_as_float(((unsigned)u)<<16); }
__device__ __forceinline__ unsigned short f2bf(float f){
  unsigned u = __float_as_uint(f);
  u += 0x7fffu + ((u>>16)&1u);
  return (unsigned short)(u>>16);
}

// fc1|fc2|qw -> bf16, plus fcsr -> transposed f32 copy (fcsrT[k][col]) in one launch
__global__ __launch_bounds__(256) void k_cast3(const float* __restrict__ fc1, const float* __restrict__ fc2,
    const float* __restrict__ qw, const float* __restrict__ fcsr,
    u16* __restrict__ w1, u16* __restrict__ w2, u16* __restrict__ qb, float* __restrict__ fT){
  int i = blockIdx.x*256 + threadIdx.x;
  if (i < 131072) w1[i] = f2bf(fc1[i]);
  else if (i < 262144) w2[i-131072] = f2bf(fc2[i-131072]);
  else if (i < 294912) qb[i-262144] = f2bf(qw[i-262144]);
  else if (i < 327680){
    int j = i - 294912;                 // j = k*128 + col
    int k = j >> 7, col = j & 127;
    fT[j] = fcsr[(size_t)col*256 + k];
  }
}

// U[r][k]: r = g*8+h (g: 0=l1,1=r1,2=l2,3=r2), rows 32..127 zero
__global__ __launch_bounds__(128) void k_prep_u(const float* __restrict__ fc1, const float* __restrict__ al1,
    const float* __restrict__ ar1, const float* __restrict__ fc2, const float* __restrict__ al2,
    const float* __restrict__ ar2, u16* __restrict__ U){
  int r = blockIdx.x, k = threadIdx.x;
  if (r >= 32){ U[(size_t)r*DD + k] = 0; return; }
  int g = r>>3, h = r&7;
  const float* fc = (g>=2)? fc2 : fc1;
  const float* av = (g==0)? al1 : (g==1)? ar1 : (g==2)? al2 : ar2;
  float s = 0.f;
  for (int d=0; d<DD; ++d) s += fc[(size_t)(h*DD+d)*DD + k] * av[h*DD+d];
  U[(size_t)r*DD + k] = f2bf(s);
}

// rows [0,NVPAD): nemb (normalized emb, bf16, pad=0); rows [NVPAD, +NITEMS): hvb = normalize(emb[iid]).
// Also zeroes cnt[0:2N).
__global__ __launch_bounds__(256) void k_norm(const float* __restrict__ emb, const int* __restrict__ iid,
    u16* __restrict__ nemb, u16* __restrict__ hvb, int* __restrict__ cnt){
  int gi = blockIdx.x*256 + threadIdx.x;
  if (gi < 2*NITEMS) cnt[gi] = 0;
  int w = gi >> 6;
  int lane = gi & 63;
  u16* dst; const float* src;
  if (w < NVPAD){
    dst = nemb + (size_t)w*DD;
    if (w >= NV){ dst[lane*2]=0; dst[lane*2+1]=0; return; }
    src = emb + (size_t)w*DD;
  } else {
    int n = w - NVPAD;
    dst = hvb + (size_t)n*DD;
    src = emb + (size_t)iid[n]*DD;
  }
  float2 v = *(const float2*)(src + lane*2);
  float ss = v.x*v.x + v.y*v.y;
  #pragma unroll
  for (int m=1;m<64;m<<=1) ss += __shfl_xor(ss, m);
  float inv = 1.f / fmaxf(sqrtf(ss), 1e-12f);
  dst[lane*2]   = f2bf(v.x*inv);
  dst[lane*2+1] = f2bf(v.y*inv);
}

// generic NT GEMM, 128x128 tile, K-step 32 (used for ecat)
template<int OUT_BF16>
__global__ __launch_bounds__(256) void gemm_nt(const u16* __restrict__ A, const u16* __restrict__ B,
                                               void* __restrict__ C, int M, int N, int K,
                                               float alpha, int ldc, int nvalid){
  __shared__ u16 As[128*32];
  __shared__ u16 Bs[128*32];
  int m0 = blockIdx.x*128, n0 = blockIdx.y*128;
  int t = threadIdx.x, lane = t&63, wid = t>>6;
  int wm = wid>>1, wn = wid&1;
  f32x4 zero = {0.f,0.f,0.f,0.f};
  f32x4 acc[4][4];
  #pragma unroll
  for (int i=0;i<4;i++)
    #pragma unroll
    for (int j=0;j<4;j++) acc[i][j] = zero;
  int lr = lane & 15, lk = (lane>>4)*8;
  for (int k0=0; k0<K; k0+=32){
    #pragma unroll
    for (int cc=0; cc<2; ++cc){
      int c = t + cc*256;
      int row = c>>2, col = (c&3)*8;
      *(bf16x8*)(void*)&As[c*8] = *(const bf16x8*)(const void*)&A[(size_t)(m0+row)*K + k0 + col];
      *(bf16x8*)(void*)&Bs[c*8] = *(const bf16x8*)(const void*)&B[(size_t)(n0+row)*K + k0 + col];
    }
    __syncthreads();
    bf16x8 af[4], bfr[4];
    #pragma unroll
    for (int m=0;m<4;m++) af[m]  = *(const bf16x8*)(const void*)&As[(wm*64+m*16+lr)*32 + lk];
    #pragma unroll
    for (int n=0;n<4;n++) bfr[n] = *(const bf16x8*)(const void*)&Bs[(wn*64+n*16+lr)*32 + lk];
    #pragma unroll
    for (int m=0;m<4;m++)
      #pragma unroll
      for (int n=0;n<4;n++)
        acc[m][n] = __builtin_amdgcn_mfma_f32_16x16x32_bf16(af[m], bfr[n], acc[m][n], 0,0,0);
    __syncthreads();
  }
  #pragma unroll
  for (int m=0;m<4;m++)
    #pragma unroll
    for (int n=0;n<4;n++)
      #pragma unroll
      for (int r=0;r<4;r++){
        int row = m0 + wm*64 + m*16 + (lane>>4)*4 + r;
        int col = n0 + wn*64 + n*16 + (lane&15);
        if (col < nvalid){
          float v = acc[m][n][r]*alpha;
          if (OUT_BF16) ((u16*)C)[(size_t)row*ldc + col] = f2bf(v);
          else          ((float*)C)[(size_t)row*ldc + col] = v;
        }
      }
}

// ---- combined CSR (keys: dst_i | NITEMS+src_i); sid stores the OTHER endpoint ----
__global__ __launch_bounds__(256) void k_deg2(const int* __restrict__ di, const int* __restrict__ si,
                                              int* __restrict__ cnt){
  int i = blockIdx.x*256+threadIdx.x;
  if (i<EINT){ atomicAdd(&cnt[di[i]],1); atomicAdd(&cnt[NITEMS+si[i]],1); }
}

__global__ __launch_bounds__(256) void k_scan_a(int* cnt, int* off, int* bsum, int n){
  __shared__ int buf[256];
  int b = blockIdx.x, t = threadIdx.x, i = b*256+t;
  int v = (i<n)? cnt[i] : 0;
  buf[t] = v; __syncthreads();
  #pragma unroll
  for (int ofs=1; ofs<256; ofs<<=1){
    int x = (t>=ofs)? buf[t-ofs] : 0;
    __syncthreads();
    buf[t] += x;
    __syncthreads();
  }
  if (i<n){ off[i] = buf[t]-v; cnt[i] = 0; }
  if (t==255) bsum[b] = buf[255];
}

__global__ __launch_bounds__(1024) void k_scan_b(int* bsum, int* off, int nb, int n){
  __shared__ int buf[1024];
  int t = threadIdx.x;
  int v = (t<nb)? bsum[t] : 0;
  buf[t]=v; __syncthreads();
  #pragma unroll
  for (int ofs=1; ofs<1024; ofs<<=1){
    int x=(t>=ofs)?buf[t-ofs]:0; __syncthreads(); buf[t]+=x; __syncthreads();
  }
  if (t<nb) bsum[t] = buf[t]-v;
  if (t==1023) off[n] = buf[1023];
}

__global__ __launch_bounds__(256) void k_scan_c(int* __restrict__ off, const int* __restrict__ bsum, int n){
  int i = blockIdx.x*256+threadIdx.x;
  if (i<n) off[i] += bsum[blockIdx.x];
}

__global__ __launch_bounds__(256) void k_scatter2(const int* __restrict__ di, const int* __restrict__ si,
    const int* __restrict__ off, int* __restrict__ cnt, int* __restrict__ sid){
  int i = blockIdx.x*256+threadIdx.x;
  if (i<EINT){
    int a = di[i];         sid[off[a]+atomicAdd(&cnt[a],1)] = si[i];
    int b = NITEMS+si[i];  sid[off[b]+atomicAdd(&cnt[b],1)] = di[i];
  }
}

// edge softmax weights, thread per node u in [0,2N), all 8 heads vectorized.
// No max-subtraction: |logit| <= ~3 so plain exp is safe and identical after normalization.
__global__ __launch_bounds__(256) void k_aw(const int* __restrict__ off, const int* __restrict__ sid,
    const float* __restrict__ ecat, u16* __restrict__ aw){
  int u = blockIdx.x*256 + threadIdx.x;
  if (u >= 2*NITEMS) return;
  int g = (u >= NITEMS) ? 1 : 0;
  int w = u - g*NITEMS;
  int cl = g*16, cr = g*16 + 8;
  float ern[8];
  #pragma unroll
  for (int h=0;h<8;h++) ern[h] = ecat[(size_t)w*32 + cr + h];
  int lo = off[u], hi = off[u+1];
  float den[8];
  #pragma unroll
  for (int h=0;h<8;h++) den[h] = 0.f;
  for (int i=lo;i<hi;++i){
    const float* e = ecat + (size_t)sid[i]*32 + cl;
    #pragma unroll
    for (int h=0;h<8;h++){
      float lv = e[h] + ern[h];
      lv = (lv>=0.f)? lv : NEG_SLOPE*lv;
      den[h] += expf(lv);
    }
  }
  float inv[8];
  #pragma unroll
  for (int h=0;h<8;h++) inv[h] = (den[h]>0.f)? 1.f/den[h] : 0.f;
  for (int i=lo;i<hi;++i){
    const float* e = ecat + (size_t)sid[i]*32 + cl;
    bf16x8 o;
    #pragma unroll
    for (int h=0;h<8;h++){
      float lv = e[h] + ern[h];
      lv = (lv>=0.f)? lv : NEG_SLOPE*lv;
      o[h] = (short)f2bf(expf(lv)*inv[h]);
    }
    *(bf16x8*)(void*)&aw[(size_t)i*8] = o;
  }
}

// Fused double-GAT v2: block = 64 nodes, 512 threads (8 waves), 1280 blocks.
// Per graph, per head-PAIR: gather both heads into a0[16]/a1[16] regs (one pass over
// edges, deg~2), stage each head's 64x128 agg tile into swizzled LDS, 128x128 MFMA
// vs fc_h with B-fragments from L2 (reused across 4 m-frags), fold bias+head-max.
// Epilogue: h = normalize(rm1 + rm2 + 2*hv) -> hb (bf16) via aliased f32 LDS tile.
__global__ __launch_bounds__(512) void k_gatfuse(const int* __restrict__ off, const int* __restrict__ sid,
    const u16* __restrict__ aw, const u16* __restrict__ hvb,
    const u16* __restrict__ wfc1, const u16* __restrict__ wfc2,
    const float* __restrict__ b1, const float* __restrict__ b2,
    u16* __restrict__ hb){
  __shared__ __align__(16) char smem[64*DD*4];   // 32 KB: aggS u16[64][128] | F f32[64][128]
  u16* aggS = (u16*)smem;
  float* F = (float*)smem;
  int n0 = blockIdx.x*64;
  int t = threadIdx.x, lane = t&63, wid = t>>6;
  int lr = lane&15, lq = lane>>4;
  int nd = t>>3, dch = t&7;          // gather role: node nd (0..63), dim chunk dch (16 dims)
  float rm[2][4][4];
  #pragma unroll
  for (int g=0;g<2;g++)
    #pragma unroll
    for (int m=0;m<4;m++)
      #pragma unroll
      for (int r=0;r<4;r++) rm[g][m][r] = -1e30f;

  #pragma unroll
  for (int g=0; g<2; ++g){
    const u16* wfc = g ? wfc2 : wfc1;
    const float* bias = g ? b2 : b1;
    int u = g*NITEMS + n0 + nd;
    int lo = off[u], hi = off[u+1];
    #pragma unroll
    for (int hp=0; hp<4; ++hp){
      // ---- gather heads 2hp, 2hp+1 into regs ----
      float a0[16], a1[16];
      #pragma unroll
      for (int j=0;j<16;j++){ a0[j]=0.f; a1[j]=0.f; }
      for (int i=lo; i<hi; ++i){
        int s = sid[i];
        bf16x8 v0 = *(const bf16x8*)(const void*)&hvb[(size_t)s*DD + dch*16];
        bf16x8 v1 = *(const bf16x8*)(const void*)&hvb[(size_t)s*DD + dch*16 + 8];
        unsigned wp = *(const unsigned*)(const void*)&aw[(size_t)i*8 + 2*hp];
        float w0 = bf2f((u16)(wp & 0xffffu)), w1 = bf2f((u16)(wp >> 16));
        #pragma unroll
        for (int j=0;j<8;j++){
          float f0 = bf2f((u16)v0[j]);
          float f1 = bf2f((u16)v1[j]);
          a0[j] += w0*f0; a0[8+j] += w0*f1;
          a1[j] += w1*f0; a1[8+j] += w1*f1;
        }
      }
      #pragma unroll
      for (int sub=0; sub<2; ++sub){
        int h = 2*hp + sub;
        const float* ap = sub ? a1 : a0;
        __syncthreads();             // previous MFMA done reading aggS
        {
          bf16x8 o0, o1;
          #pragma unroll
          for (int j=0;j<8;j++){ o0[j] = (short)f2bf(ap[j]); o1[j] = (short)f2bf(ap[8+j]); }
          *(bf16x8*)(void*)&aggS[nd*DD + (((dch*2)   ^ (nd&7))*8)] = o0;
          *(bf16x8*)(void*)&aggS[nd*DD + (((dch*2+1) ^ (nd&7))*8)] = o1;
        }
        __syncthreads();
        // ---- MFMA: wave covers cols wid*16..+16, all 64 rows ----
        f32x4 acc[4];
        #pragma unroll
        for (int m=0;m<4;m++){ f32x4 z={0.f,0.f,0.f,0.f}; acc[m]=z; }
        #pragma unroll
        for (int ks=0; ks<4; ++ks){
          bf16x8 bfr = *(const bf16x8*)(const void*)&wfc[(size_t)(h*DD + wid*16 + lr)*DD + ks*32 + lq*8];
          #pragma unroll
          for (int m=0;m<4;m++){
            int row = m*16 + lr;
            bf16x8 af = *(const bf16x8*)(const void*)&aggS[row*DD + ((((ks*4+lq) ^ (row&7)))*8)];
            acc[m] = __builtin_amdgcn_mfma_f32_16x16x32_bf16(af, bfr, acc[m], 0,0,0);
          }
        }
        float bn = bias[h*DD + wid*16 + lr];
        #pragma unroll
        for (int m=0;m<4;m++)
          #pragma unroll
          for (int r=0;r<4;r++)
            rm[g][m][r] = fmaxf(rm[g][m][r], acc[m][r] + bn);
      }
    }
  }
  // ---- epilogue: tot = rm1 + rm2 + 2*hv; h = normalize(tot) -> hb ----
  __syncthreads();                   // last MFMA done; F aliases aggS
  #pragma unroll
  for (int m=0;m<4;m++)
    #pragma unroll
    for (int r=0;r<4;r++){
      int row = m*16 + lq*4 + r;
      int col = wid*16 + lr;
      float hvv = bf2f(hvb[(size_t)(n0+row)*DD + col]);
      F[row*DD + col] = rm[0][m][r] + rm[1][m][r] + 2.f*hvv;
    }
  __syncthreads();
  {
    int r8 = t>>3, q = t&7;          // row r8, 16-col slice q
    float ss = 0.f;
    #pragma unroll
    for (int j=0;j<16;j+=4){
      float4 v4 = *(const float4*)&F[r8*DD + q*16 + j];
      ss += v4.x*v4.x + v4.y*v4.y + v4.z*v4.z + v4.w*v4.w;
    }
    ss += __shfl_xor(ss,1); ss += __shfl_xor(ss,2); ss += __shfl_xor(ss,4);
    float inv = 1.f/fmaxf(sqrtf(ss),1e-12f);
    #pragma unroll
    for (int j=0;j<16;j+=4){
      float4 v4 = *(const float4*)&F[r8*DD + q*16 + j];
      u16x4 o = {f2bf(v4.x*inv), f2bf(v4.y*inv), f2bf(v4.z*inv), f2bf(v4.w*inv)};
      *(u16x4*)(void*)&hb[(size_t)(n0+r8)*DD + q*16 + j] = o;
    }
  }
}

// ep GEMM with gathered A rows ([hb[asrc]|pemb[pid]] built in staging) and fused
// w-epilogue: w[i] = sum_j tanh(ep[i,j]) * temb[tid[adst[i]], j]. Writes only wv.
__global__ __launch_bounds__(256) void k_epw(const int* __restrict__ asrc, const int* __restrict__ pid,
    const int* __restrict__ adst, const int* __restrict__ tid_, const u16* __restrict__ hb,
    const float* __restrict__ pemb, const u16* __restrict__ qwb, const float* __restrict__ temb,
    float* __restrict__ wv){
  __shared__ u16 As[128*32];
  __shared__ u16 Bs[128*32];
  __shared__ float tembS[10*DD];
  __shared__ float wsum[128];
  __shared__ int rowtt[128];
  int m0 = blockIdx.x*128;
  int t = threadIdx.x, lane = t&63, wid = t>>6;
  int wm = wid>>1, wn = wid&1, lr = lane&15, lq = lane>>4;
  for (int i=t; i<10*DD; i+=256) tembS[i] = temb[i];
  if (t < 128){ rowtt[t] = tid_[adst[m0+t]]; wsum[t] = 0.f; }
  f32x4 zero = {0.f,0.f,0.f,0.f};
  f32x4 acc[4][4];
  #pragma unroll
  for (int i=0;i<4;i++)
    #pragma unroll
    for (int j=0;j<4;j++) acc[i][j] = zero;
  for (int k0=0; k0<256; k0+=32){
    #pragma unroll
    for (int cc=0; cc<2; ++cc){
      int c = t + cc*256;
      int row = c>>2;
      int kk = k0 + (c&3)*8;
      bf16x8 av;
      if (k0 < 128){
        av = *(const bf16x8*)(const void*)&hb[(size_t)asrc[m0+row]*DD + kk];
      } else {
        const float* p = pemb + (size_t)pid[m0+row]*DD + (kk-128);
        float4 p0 = *(const float4*)p;
        float4 p1 = *(const float4*)(p+4);
        av[0]=(short)f2bf(p0.x); av[1]=(short)f2bf(p0.y); av[2]=(short)f2bf(p0.z); av[3]=(short)f2bf(p0.w);
        av[4]=(short)f2bf(p1.x); av[5]=(short)f2bf(p1.y); av[6]=(short)f2bf(p1.z); av[7]=(short)f2bf(p1.w);
      }
      *(bf16x8*)(void*)&As[c*8] = av;
      *(bf16x8*)(void*)&Bs[c*8] = *(const bf16x8*)(const void*)&qwb[(size_t)row*256 + kk];
    }
    __syncthreads();
    bf16x8 af[4], bfr[4];
    #pragma unroll
    for (int m=0;m<4;m++) af[m]  = *(const bf16x8*)(const void*)&As[(wm*64+m*16+lr)*32 + lq*8];
    #pragma unroll
    for (int n=0;n<4;n++) bfr[n] = *(const bf16x8*)(const void*)&Bs[(wn*64+n*16+lr)*32 + lq*8];
    #pragma unroll
    for (int m=0;m<4;m++)
      #pragma unroll
      for (int n=0;n<4;n++)
        acc[m][n] = __builtin_amdgcn_mfma_f32_16x16x32_bf16(af[m], bfr[n], acc[m][n], 0,0,0);
    __syncthreads();
  }
  // epilogue: per-row weighted tanh reduction
  #pragma unroll
  for (int m=0;m<4;m++)
    #pragma unroll
    for (int r=0;r<4;r++){
      int lrow = wm*64 + m*16 + lq*4 + r;
      int tt = rowtt[lrow];
      float p = 0.f;
      #pragma unroll
      for (int n=0;n<4;n++){
        int col = wn*64 + n*16 + lr;
        p += tanhf(acc[m][n][r]) * tembS[tt*DD + col];
      }
      #pragma unroll
      for (int msk=1; msk<16; msk<<=1) p += __shfl_xor(p, msk);
      if (lr==0) atomicAdd(&wsum[lrow], p);
    }
  __syncthreads();
  if (t < 128) wv[m0+t] = wsum[t];
}

__device__ __forceinline__ int lbound(const int* a, int n, int key){
  int lo=0, hi=n;
  while (lo<hi){ int mid=(lo+hi)>>1; if (a[mid]<key) lo=mid+1; else hi=mid; }
  return lo;
}

// per-target: sr_g segment sum (hb rows, f32 accum), concat h[last], fc_srT matvec (coalesced), normalize
__global__ __launch_bounds__(256) void k_sr(const u16* __restrict__ hb, const float* __restrict__ w,
    const int* __restrict__ asrc, const int* __restrict__ adst, const int* __restrict__ lastn,
    const float* __restrict__ fcsrT, u16* __restrict__ nsr){
  __shared__ float cat[256];
  __shared__ float red[128];
  __shared__ int lohi[2];
  int t = blockIdx.x, tid = threadIdx.x;
  if (tid == 0){ lohi[0] = lbound(adst, EAGG, t); lohi[1] = lbound(adst, EAGG, t+1); }
  __syncthreads();
  int lo = lohi[0], hi = lohi[1];
  if (tid < DD){
    float a = 0.f;
    for (int i=lo;i<hi;++i) a += bf2f(hb[(size_t)asrc[i]*DD + tid]) * w[i];
    cat[tid] = a;
  } else {
    int d = tid - DD;
    cat[DD + d] = bf2f(hb[(size_t)lastn[t]*DD + d]);
  }
  __syncthreads();
  float s = 0.f;
  if (tid < DD){
    #pragma unroll 8
    for (int k=0;k<256;++k) s += cat[k]*fcsrT[(size_t)k*DD + tid];
    red[tid] = s*s;
  }
  __syncthreads();
  for (int st=64; st>0; st>>=1){
    if (tid < st) red[tid] += red[tid+st];
    __syncthreads();
  }
  if (tid < DD){
    float inv = 1.f/fmaxf(sqrtf(red[0]),1e-12f);
    nsr[(size_t)t*DD + tid] = f2bf(s*inv);
  }
}

// scores GEMM: K=128 (4 steps), XCD-chunked swizzle, LDS-transpose epilogue (dwordx4 stores)
__global__ __launch_bounds__(256) void gemm_sc(const u16* __restrict__ A, const u16* __restrict__ B,
                                               float* __restrict__ C){
  __shared__ __align__(16) char smem[16384];
  u16* As = (u16*)smem;            // [128*32]
  u16* Bs = As + 4096;             // [128*32]
  float* tr = (float*)smem;        // 4096 f32, reused after K-loop
  int flat = blockIdx.y*gridDim.x + blockIdx.x;     // 10016 = 8*1252, x fastest
  int nf = (flat&7)*1252 + (flat>>3);
  int m0 = (nf & 31)*128;
  int n0 = (nf >> 5)*128;
  int t = threadIdx.x, lane = t&63, wid = t>>6;
  int wm = wid>>1, wn = wid&1, lr = lane&15, lq = lane>>4;
  f32x4 zero = {0.f,0.f,0.f,0.f};
  f32x4 acc[4][4];
  #pragma unroll
  for (int i=0;i<4;i++)
    #pragma unroll
    for (int j=0;j<4;j++) acc[i][j] = zero;
  for (int k0=0; k0<DD; k0+=32){
    #pragma unroll
    for (int cc=0; cc<2; ++cc){
      int c = t + cc*256;
      int row = c>>2, col = (c&3)*8;
      *(bf16x8*)(void*)&As[c*8] = *(const bf16x8*)(const void*)&A[(size_t)(m0+row)*DD + k0 + col];
      *(bf16x8*)(void*)&Bs[c*8] = *(const bf16x8*)(const void*)&B[(size_t)(n0+row)*DD + k0 + col];
    }
    __syncthreads();
    bf16x8 af[4], bfr[4];
    #pragma unroll
    for (int m=0;m<4;m++) af[m]  = *(const bf16x8*)(const void*)&As[(wm*64+m*16+lr)*32 + lq*8];
    #pragma unroll
    for (int n=0;n<4;n++) bfr[n] = *(const bf16x8*)(const void*)&Bs[(wn*64+n*16+lr)*32 + lq*8];
    #pragma unroll
    for (int m=0;m<4;m++)
      #pragma unroll
      for (int n=0;n<4;n++)
        acc[m][n] = __builtin_amdgcn_mfma_f32_16x16x32_bf16(af[m], bfr[n], acc[m][n], 0,0,0);
    __syncthreads();
  }
  // transpose-in-LDS epilogue: per m-chunk, wave tile 16 rows x 64 cols -> dwordx4 stores
  #pragma unroll
  for (int m=0;m<4;m++){
    #pragma unroll
    for (int n=0;n<4;n++)
      #pragma unroll
      for (int r=0;r<4;r++)
        tr[wid*1024 + (lq*4+r)*64 + n*16 + lr] = acc[m][n][r]*SCALE;
    __syncthreads();
    int row16 = lane>>2, ch = (lane&3)*16;
    int grow = m0 + wm*64 + m*16 + row16;
    int gcol = n0 + wn*64 + ch;
    if (gcol < NV){
      const float* s = &tr[wid*1024 + row16*64 + ch];
      float* d = &C[(size_t)grow*NV + gcol];
      *(float4*)(d)    = *(const float4*)(s);
      *(float4*)(d+4)  = *(const float4*)(s+4);
      *(float4*)(d+8)  = *(const float4*)(s+8);
      *(float4*)(d+12) = *(const float4*)(s+12);
    }
    __syncthreads();
  }
}

extern "C" void kernel_launch(void* const* d_in, const int* in_sizes, int n_in,
                              void* d_out, int out_size, void* d_ws, size_t ws_size,
                              hipStream_t stream){
  (void)in_sizes; (void)n_in; (void)out_size; (void)ws_size;
  const int*   iid   = (const int*)d_in[0];
  const int*   tid_  = (const int*)d_in[1];
  const int*   pid   = (const int*)d_in[2];
  const int*   src_i = (const int*)d_in[3];
  const int*   dst_i = (const int*)d_in[4];
  const int*   asrc  = (const int*)d_in[5];
  const int*   adst  = (const int*)d_in[6];
  const int*   lastn = (const int*)d_in[7];
  const float* emb   = (const float*)d_in[8];
  const float* pemb  = (const float*)d_in[9];
  const float* temb  = (const float*)d_in[10];
  const float* fc1   = (const float*)d_in[11];
  const float* al1   = (const float*)d_in[12];
  const float* ar1   = (const float*)d_in[13];
  const float* b1    = (const float*)d_in[14];
  const float* fc2   = (const float*)d_in[15];
  const float* al2   = (const float*)d_in[16];
  const float* ar2   = (const float*)d_in[17];
  const float* b2    = (const float*)d_in[18];
  const float* qw    = (const float*)d_in[19];
  const float* fcsr  = (const float*)d_in[20];

  char* ws = (char*)d_ws;
  size_t o = 0;
  auto alc = [&](size_t b)->char*{ char* r = ws + o; o += (b + 511) & ~(size_t)511; return r; };
  u16*   hvb  = (u16*)  alc((size_t)NITEMS*DD*2);      // 21 MB
  u16*   hb   = (u16*)  alc((size_t)NITEMS*DD*2);      // 21 MB
  float* ecat = (float*)alc((size_t)NITEMS*32*4);      // 10.5 MB (el1|er1|el2|er2)
  int*   off  = (int*)  alc((size_t)(2*NITEMS+1)*4);
  int*   cnt  = (int*)  alc((size_t)(2*NITEMS)*4);
  int*   bsum = (int*)  alc((size_t)1024*4);
  int*   sid  = (int*)  alc((size_t)(2*EINT)*4);       // 1.3 MB
  u16*   aw   = (u16*)  alc((size_t)(2*EINT)*8*2);     // 5.2 MB
  u16*   wfc1 = (u16*)  alc((size_t)1024*DD*2);
  u16*   wfc2 = (u16*)  alc((size_t)1024*DD*2);
  u16*   qwb  = (u16*)  alc((size_t)DD*256*2);
  float* fT   = (float*)alc((size_t)256*DD*4);         // fcsr transposed (f32)
  u16*   Umat = (u16*)  alc((size_t)128*DD*2);
  float* wv   = (float*)alc((size_t)EAGG*4);
  u16*   nsr  = (u16*)  alc((size_t)NT*DD*2);
  u16*   nemb = (u16*)  alc((size_t)NVPAD*DD*2);       // 10.3 MB

  const int N2 = 2*NITEMS;
  const int NB2 = N2/256;    // 640

  // prep (also zeroes cnt)
  k_norm<<<(NVPAD+NITEMS)/4, 256, 0, stream>>>(emb, iid, nemb, hvb, cnt);
  k_prep_u<<<128, 128, 0, stream>>>(fc1, al1, ar1, fc2, al2, ar2, Umat);
  k_cast3<<<1280, 256, 0, stream>>>(fc1, fc2, qw, fcsr, wfc1, wfc2, qwb, fT);
  gemm_nt<0><<<dim3(NITEMS/128, 1), 256, 0, stream>>>(hvb, Umat, ecat, NITEMS, 128, DD, 1.f, 32, 32);

  // combined CSR
  k_deg2<<<(EINT+255)/256, 256, 0, stream>>>(dst_i, src_i, cnt);
  k_scan_a<<<NB2, 256, 0, stream>>>(cnt, off, bsum, N2);
  k_scan_b<<<1, 1024, 0, stream>>>(bsum, off, NB2, N2);
  k_scan_c<<<NB2, 256, 0, stream>>>(off, bsum, N2);
  k_scatter2<<<(EINT+255)/256, 256, 0, stream>>>(dst_i, src_i, off, cnt, sid);

  // edge softmax weights (both graphs, all heads)
  k_aw<<<N2/256, 256, 0, stream>>>(off, sid, ecat, aw);

  // fused double-GAT -> hb
  k_gatfuse<<<NITEMS/64, 512, 0, stream>>>(off, sid, aw, hvb, wfc1, wfc2, b1, b2, hb);

  // PosAggregator: ep GEMM with gathered A + fused w epilogue
  k_epw<<<EAGG/128, 256, 0, stream>>>(asrc, pid, adst, tid_, hb, pemb, qwb, temb, wv);
  k_sr<<<NT, 256, 0, stream>>>(hb, wv, asrc, adst, lastn, fT, nsr);

  // scores
  gemm_sc<<<dim3(32, NVPAD/128), 256, 0, stream>>>(nsr, nemb, (float*)d_out);
}